// Round 4
// baseline (614.848 us; speedup 1.0000x reference)
//
#include <hip/hip_runtime.h>
#include <math.h>

#define BB 16
#define SS 16
#define VVV 64
#define EE 64
#define HHH 8
#define NLAYER 4
#define DFF_ 2048
#define LL 1024   /* S*V */
#define BL 16384  /* B*L */
#define PERL 131072  /* 64*2048 elems per layer of W1 (and W2) */

typedef __attribute__((ext_vector_type(8))) _Float16 half8;
typedef __attribute__((ext_vector_type(4))) _Float16 half4v;
typedef __attribute__((ext_vector_type(4))) float f32x4;

// XOR-swizzled index into row-major fp16 LDS tiles (16B granules, conflict-free)
#define SW64(m, k)  (((m) << 6) + ((((k) >> 3) ^ ((m) & 7)) << 3) + ((k) & 7))
#define SW128(m, k) (((m) << 7) + ((((k) >> 3) ^ ((m) & 7)) << 3) + ((k) & 7))

// ---------------- coalesced transpose + fp32->fp16: dst[c][r] = src[r][c] ----------------
__global__ __launch_bounds__(256) void k_tr(
    const float* __restrict__ src, _Float16* __restrict__ dst,
    int R, int C, long lsrc, long ldst)
{
  __shared__ float t[64][65];
  const float* s = src + (size_t)blockIdx.z * lsrc;
  _Float16* d = dst + (size_t)blockIdx.z * ldst;
  int c0 = blockIdx.x * 64, r0 = blockIdx.y * 64;
  int cc = threadIdx.x & 63, rr = threadIdx.x >> 6;
#pragma unroll
  for (int i = 0; i < 16; i++) {
    int r = i * 4 + rr;
    if (r0 + r < R && c0 + cc < C)
      t[r][cc] = s[(size_t)(r0 + r) * C + c0 + cc];
  }
  __syncthreads();
#pragma unroll
  for (int i = 0; i < 16; i++) {
    int c = i * 4 + rr;
    if (c0 + c < C && r0 + cc < R)
      d[(size_t)(c0 + c) * R + r0 + cc] = (_Float16)t[cc][c];
  }
}

// ------- fused embed + comb GEMM: x = concat@W_comb + b_comb + pos + type; also zm -------
__global__ __launch_bounds__(256) void k_embcomb(
    const float* __restrict__ features, const int* __restrict__ ovtag,
    const int* __restrict__ poiid, const float* __restrict__ W_raw,
    const float* __restrict__ b_raw, const float* __restrict__ ov_tab,
    const float* __restrict__ poi_tab, const _Float16* __restrict__ wcombt,
    const float* __restrict__ b_comb, const float* __restrict__ pos_tab,
    const float* __restrict__ type_tab, float* __restrict__ x,
    float* __restrict__ zm)
{
  constexpr int KP = 104;  // 96 + 8 halves pad
  __shared__ _Float16 As[64 * KP];
  __shared__ _Float16 Bs[64 * KP];
  int tid = threadIdx.x;
  int m0 = blockIdx.x * 64;
  int wave = tid >> 6, lane = tid & 63, quad = lane >> 4, l15 = lane & 15;
  int wm = wave >> 1, wn = wave & 1;
  // build concat tile directly in LDS (fp16)
  for (int p = tid; p < 1536; p += 256) {
    int r = p / 24, s = p - r * 24; int c = s * 4;
    int row = m0 + r;
    float f0 = features[row * 3 + 0];
    float f1 = features[row * 3 + 1];
    float f2 = features[row * 3 + 2];
    if (s == 0) zm[row] = ((f0 + f1 + f2) == 0.f) ? 1.f : 0.f;
    half4v h;
#pragma unroll
    for (int j = 0; j < 4; j++) {
      int cc = c + j; float v;
      if (cc < 64) {
        v = b_raw[cc] + f0 * W_raw[cc] + f1 * W_raw[64 + cc] + f2 * W_raw[128 + cc];
      } else if (cc < 72) {
        int t = ovtag[row]; v = (t <= 0) ? 0.f : ov_tab[t * 8 + cc - 64];
      } else if (cc < 80) {
        int t = poiid[row]; v = (t <= 0) ? 0.f : poi_tab[t * 8 + cc - 72];
      } else v = 0.f;
      h[j] = (_Float16)v;
    }
    *(half4v*)&As[r * KP + c] = h;
  }
  for (int p = tid; p < 1536; p += 256) {
    int r = p / 24, s = p - r * 24; int c = s * 4;
    half4v h = (half4v){0, 0, 0, 0};
    if (c < 80) h = *(const half4v*)&wcombt[r * 80 + c];
    *(half4v*)&Bs[r * KP + c] = h;
  }
  __syncthreads();
  f32x4 acc[2][2];
#pragma unroll
  for (int mt = 0; mt < 2; mt++)
#pragma unroll
    for (int nt = 0; nt < 2; nt++) {
      float bv = b_comb[wn * 32 + nt * 16 + l15];
      acc[mt][nt] = (f32x4){bv, bv, bv, bv};
    }
#pragma unroll
  for (int ks = 0; ks < 3; ks++) {
    half8 af[2], bf[2];
#pragma unroll
    for (int mt = 0; mt < 2; mt++)
      af[mt] = *(const half8*)&As[(wm * 32 + mt * 16 + l15) * KP + ks * 32 + quad * 8];
#pragma unroll
    for (int nt = 0; nt < 2; nt++)
      bf[nt] = *(const half8*)&Bs[(wn * 32 + nt * 16 + l15) * KP + ks * 32 + quad * 8];
#pragma unroll
    for (int mt = 0; mt < 2; mt++)
#pragma unroll
      for (int nt = 0; nt < 2; nt++)
        acc[mt][nt] = __builtin_amdgcn_mfma_f32_16x16x32_f16(af[mt], bf[nt],
                                                             acc[mt][nt], 0, 0, 0);
  }
#pragma unroll
  for (int mt = 0; mt < 2; mt++)
#pragma unroll
    for (int nt = 0; nt < 2; nt++)
#pragma unroll
      for (int r = 0; r < 4; r++) {
        int row = m0 + wm * 32 + mt * 16 + quad * 4 + r;
        int col = wn * 32 + nt * 16 + l15;
        int l = row & (LL - 1);
        x[(size_t)row * 64 + col] = acc[mt][nt][r] +
            pos_tab[(l >> 6) * 64 + col] + type_tab[(l & 63) * 64 + col];
      }
}

// ---------------- fp16 MFMA GEMM (QKV): C[M,N] = A[M,64]@Bt[N,64]^T + bias ----------------
__global__ __launch_bounds__(256) void k_gemm16(
    const float* __restrict__ A, const _Float16* __restrict__ Bt,
    const float* __restrict__ bias, float* __restrict__ C, int N)
{
  constexpr int KP = 72;
  __shared__ _Float16 As[64 * KP];
  __shared__ _Float16 Bs[64 * KP];
  int tid = threadIdx.x;
  int m0 = blockIdx.x * 64, n0 = blockIdx.y * 64;
  int wave = tid >> 6, lane = tid & 63, quad = lane >> 4, l15 = lane & 15;
  int wm = wave >> 1, wn = wave & 1;
  for (int p = tid; p < 1024; p += 256) {
    int r = p >> 4, c = (p & 15) << 2;
    float4 f = *(const float4*)&A[(size_t)(m0 + r) * 64 + c];
    *(half4v*)&As[r * KP + c] =
        (half4v){(_Float16)f.x, (_Float16)f.y, (_Float16)f.z, (_Float16)f.w};
  }
  for (int p = tid; p < 1024; p += 256) {
    int r = p >> 4, c = (p & 15) << 2;
    *(half4v*)&Bs[r * KP + c] = *(const half4v*)&Bt[(size_t)(n0 + r) * 64 + c];
  }
  __syncthreads();
  f32x4 acc[2][2];
#pragma unroll
  for (int mt = 0; mt < 2; mt++)
#pragma unroll
    for (int nt = 0; nt < 2; nt++) {
      float bv = bias[n0 + wn * 32 + nt * 16 + l15];
      acc[mt][nt] = (f32x4){bv, bv, bv, bv};
    }
#pragma unroll
  for (int ks = 0; ks < 2; ks++) {
    half8 af[2], bf[2];
#pragma unroll
    for (int mt = 0; mt < 2; mt++)
      af[mt] = *(const half8*)&As[(wm * 32 + mt * 16 + l15) * KP + ks * 32 + quad * 8];
#pragma unroll
    for (int nt = 0; nt < 2; nt++)
      bf[nt] = *(const half8*)&Bs[(wn * 32 + nt * 16 + l15) * KP + ks * 32 + quad * 8];
#pragma unroll
    for (int mt = 0; mt < 2; mt++)
#pragma unroll
      for (int nt = 0; nt < 2; nt++)
        acc[mt][nt] = __builtin_amdgcn_mfma_f32_16x16x32_f16(af[mt], bf[nt],
                                                             acc[mt][nt], 0, 0, 0);
  }
#pragma unroll
  for (int mt = 0; mt < 2; mt++)
#pragma unroll
    for (int nt = 0; nt < 2; nt++)
#pragma unroll
      for (int r = 0; r < 4; r++) {
        int row = m0 + wm * 32 + mt * 16 + quad * 4 + r;
        int col = n0 + wn * 32 + nt * 16 + l15;
        C[(size_t)row * N + col] = acc[mt][nt][r];
      }
}

// ---------------- attention: block = (b, h, 256 q-rows); masked online softmax ----------------
__global__ __launch_bounds__(256) void k_attn(
    const float* __restrict__ qkv, const float* __restrict__ zm,
    float* __restrict__ obuf)
{
  __shared__ float KsT[8 * 1024];
  __shared__ float VsT[8 * 1024];
  int blk = blockIdx.x;
  int qb = blk & 3, h = (blk >> 2) & 7, b = blk >> 5;
  const float* base = qkv + (size_t)b * LL * 192;
  for (int p = threadIdx.x; p < 8192; p += 256) {
    int k = p >> 3, d = p & 7;
    KsT[d * 1024 + k] = base[(size_t)k * 192 + 64 + h * 8 + d];
    VsT[d * 1024 + k] = base[(size_t)k * 192 + 128 + h * 8 + d];
  }
  __syncthreads();
  int qrow = qb * 256 + threadIdx.x;
  int tq = qrow >> 6, vq = qrow & 63;
  const float* zmb = zm + b * LL;
  float q[8];
#pragma unroll
  for (int d = 0; d < 8; d++) q[d] = base[(size_t)qrow * 192 + h * 8 + d];
  const float scale = 0.3535533905932738f;
  float m = -INFINITY, lsum = 0.f;
  float acc[8] = {0.f, 0.f, 0.f, 0.f, 0.f, 0.f, 0.f, 0.f};
  bool zmq = (zmb[qrow] != 0.f);

  auto attend = [&](int k) {
    if (zmb[k] != 0.f) return;
    float s = 0.f;
#pragma unroll
    for (int d = 0; d < 8; d++) s += q[d] * KsT[d * 1024 + k];
    s *= scale;
    if (s <= m) {
      float p = __expf(s - m);
      lsum += p;
#pragma unroll
      for (int d = 0; d < 8; d++) acc[d] += p * VsT[d * 1024 + k];
    } else {
      float r = __expf(m - s);
      lsum = lsum * r + 1.f;
#pragma unroll
      for (int d = 0; d < 8; d++) acc[d] = acc[d] * r + VsT[d * 1024 + k];
      m = s;
    }
  };

  if (!zmq) {
    for (int vv = 0; vv < 64; vv++) attend(tq * 64 + vv);
    for (int tt = 0; tt < 16; tt++) {
      if (tt == tq) continue;
      attend(tt * 64 + vq);
    }
  }
  float inv = 1.f / lsum;
  float* orow = obuf + (size_t)(b * LL + qrow) * 64 + h * 8;
#pragma unroll
  for (int d = 0; d < 8; d++) orow[d] = acc[d] * inv;
}

// ---------------- fused o-proj + residual + LN1: x = LN(x + o@Wo + bo) ----------------
__global__ __launch_bounds__(256) void k_oln(
    const float* __restrict__ obuf, const _Float16* __restrict__ wot,
    const float* __restrict__ bo, float* __restrict__ x,
    const float* __restrict__ ln_s, const float* __restrict__ ln_b)
{
  constexpr int KP = 72;
  __shared__ _Float16 As[64 * KP];
  __shared__ _Float16 Bs[64 * KP];
  __shared__ float ots[64 * 68];
  int tid = threadIdx.x;
  int m0 = blockIdx.x * 64;
  int wave = tid >> 6, lane = tid & 63, quad = lane >> 4, l15 = lane & 15;
  int wm = wave >> 1, wn = wave & 1;
  for (int p = tid; p < 1024; p += 256) {
    int r = p >> 4, c = (p & 15) << 2;
    float4 f = *(const float4*)&obuf[(size_t)(m0 + r) * 64 + c];
    *(half4v*)&As[r * KP + c] =
        (half4v){(_Float16)f.x, (_Float16)f.y, (_Float16)f.z, (_Float16)f.w};
  }
  for (int p = tid; p < 1024; p += 256) {
    int r = p >> 4, c = (p & 15) << 2;
    *(half4v*)&Bs[r * KP + c] = *(const half4v*)&wot[(size_t)r * 64 + c];
  }
  __syncthreads();
  f32x4 acc[2][2];
#pragma unroll
  for (int mt = 0; mt < 2; mt++)
#pragma unroll
    for (int nt = 0; nt < 2; nt++) {
      float bv = bo[wn * 32 + nt * 16 + l15];
      acc[mt][nt] = (f32x4){bv, bv, bv, bv};
    }
#pragma unroll
  for (int ks = 0; ks < 2; ks++) {
    half8 af[2], bf[2];
#pragma unroll
    for (int mt = 0; mt < 2; mt++)
      af[mt] = *(const half8*)&As[(wm * 32 + mt * 16 + l15) * KP + ks * 32 + quad * 8];
#pragma unroll
    for (int nt = 0; nt < 2; nt++)
      bf[nt] = *(const half8*)&Bs[(wn * 32 + nt * 16 + l15) * KP + ks * 32 + quad * 8];
#pragma unroll
    for (int mt = 0; mt < 2; mt++)
#pragma unroll
      for (int nt = 0; nt < 2; nt++)
        acc[mt][nt] = __builtin_amdgcn_mfma_f32_16x16x32_f16(af[mt], bf[nt],
                                                             acc[mt][nt], 0, 0, 0);
  }
#pragma unroll
  for (int mt = 0; mt < 2; mt++)
#pragma unroll
    for (int nt = 0; nt < 2; nt++)
#pragma unroll
      for (int r = 0; r < 4; r++)
        ots[(wm * 32 + mt * 16 + quad * 4 + r) * 68 + wn * 32 + nt * 16 + l15] =
            acc[mt][nt][r];
  __syncthreads();
  // LN: 4 waves x 16 rows, lane = dim
  for (int i = 0; i < 16; i++) {
    int row = wave * 16 + i;
    size_t off = (size_t)(m0 + row) * 64 + lane;
    float val = ots[row * 68 + lane] + x[off];
    float sum = val;
#pragma unroll
    for (int o = 32; o > 0; o >>= 1) sum += __shfl_xor(sum, o);
    float mean = sum * (1.f / 64.f);
    float d = val - mean;
    float sq = d * d;
#pragma unroll
    for (int o = 32; o > 0; o >>= 1) sq += __shfl_xor(sq, o);
    x[off] = d * rsqrtf(sq * (1.f / 64.f) + 1e-5f) * ln_s[lane] + ln_b[lane];
  }
}

// -------- fused FFN + residual + LN2 (512 thr): x = LN(x + relu(x@W1+b1)@W2 + b2) --------
__global__ __launch_bounds__(512) void k_ffn2(
    const float* __restrict__ x, const _Float16* __restrict__ w1t,
    const _Float16* __restrict__ w2t, const float* __restrict__ b1,
    const float* __restrict__ b2, const float* __restrict__ ln_s,
    const float* __restrict__ ln_b)
{
  __shared__ char smem[57344];
  _Float16* xs  = (_Float16*)smem;             // 64x64 halves (8 KB)
  _Float16* ws1 = (_Float16*)(smem + 8192);    // 128x64 halves (16 KB)
  _Float16* ws2 = (_Float16*)(smem + 24576);   // 64x128 halves (16 KB)
  _Float16* hs  = (_Float16*)(smem + 40960);   // 64x128 halves (16 KB)
  float* ots    = (float*)(smem + 8192);       // 64x68 fp32, aliases ws1/ws2

  int tid = threadIdx.x;
  int r0 = blockIdx.x * 64;
  int wave = tid >> 6, lane = tid & 63;
  int quad = lane >> 4, l15 = lane & 15;
  int wa = wave >> 1, wb = wave & 1;   // 4x2 wave grid

  const float* xt = x + (size_t)r0 * 64;
  for (int p = tid; p < 1024; p += 512) {
    int m = p >> 4, c = (p & 15) << 2;
    float4 f = *(const float4*)&xt[m * 64 + c];
    *(half4v*)&xs[SW64(m, c)] =
        (half4v){(_Float16)f.x, (_Float16)f.y, (_Float16)f.z, (_Float16)f.w};
  }
  __syncthreads();

  // hoist x B-frags for GEMM1^T (cols m = wb*32 + mt*16 + l15)
  half8 xb[2][2];
#pragma unroll
  for (int mt = 0; mt < 2; mt++)
#pragma unroll
    for (int ks = 0; ks < 2; ks++)
      xb[mt][ks] = *(const half8*)&xs[SW64(wb * 32 + mt * 16 + l15, ks * 32 + quad * 8)];

  f32x4 acc[2];  // GEMM2: rows wa*16+quad*4+r, cols wb*32+nt*16+l15
#pragma unroll
  for (int nt = 0; nt < 2; nt++) {
    float bv = b2[wb * 32 + nt * 16 + l15];
    acc[nt] = (f32x4){bv, bv, bv, bv};
  }

  for (int i = 0; i < 16; i++) {
    int hb = i * 128;
    __syncthreads();  // prev iter's reads of ws1/ws2/hs complete
    for (int p = tid; p < 2048; p += 512) {
      int r = p >> 4, s = (p & 15) << 2;
      *(half4v*)&ws1[SW64(r, s)] = *(const half4v*)&w1t[(size_t)(hb + r) * 64 + s];
    }
    for (int p = tid; p < 2048; p += 512) {
      int r = p >> 5, s = (p & 31) << 2;
      *(half4v*)&ws2[SW128(r, s)] = *(const half4v*)&w2t[(size_t)r * 2048 + hb + s];
    }
    __syncthreads();
    // GEMM1^T: Ht[128 hid][64 m]; wave tile: hid 32 (wa), m 32 (wb)
    f32x4 hacc[2][2];
#pragma unroll
    for (int ht = 0; ht < 2; ht++)
#pragma unroll
      for (int mt = 0; mt < 2; mt++) hacc[ht][mt] = (f32x4){0.f, 0.f, 0.f, 0.f};
#pragma unroll
    for (int ks = 0; ks < 2; ks++) {
      half8 a1[2];
#pragma unroll
      for (int ht = 0; ht < 2; ht++)
        a1[ht] = *(const half8*)&ws1[SW64(wa * 32 + ht * 16 + l15, ks * 32 + quad * 8)];
#pragma unroll
      for (int ht = 0; ht < 2; ht++)
#pragma unroll
        for (int mt = 0; mt < 2; mt++)
          hacc[ht][mt] = __builtin_amdgcn_mfma_f32_16x16x32_f16(
              a1[ht], xb[mt][ks], hacc[ht][mt], 0, 0, 0);
    }
    // bias + relu + pack to hs[m][hid] (b64 writes: 4 consecutive hid per quad)
#pragma unroll
    for (int ht = 0; ht < 2; ht++) {
      int hr = wa * 32 + ht * 16 + quad * 4;
      float4 bb = *(const float4*)&b1[hb + hr];
#pragma unroll
      for (int mt = 0; mt < 2; mt++) {
        int m = wb * 32 + mt * 16 + l15;
        f32x4 h = hacc[ht][mt];
        half4v hp = (half4v){
            (_Float16)fmaxf(h[0] + bb.x, 0.f), (_Float16)fmaxf(h[1] + bb.y, 0.f),
            (_Float16)fmaxf(h[2] + bb.z, 0.f), (_Float16)fmaxf(h[3] + bb.w, 0.f)};
        *(half4v*)&hs[SW128(m, hr)] = hp;
      }
    }
    __syncthreads();  // hs visible
    // GEMM2: acc += H[m][hid128] @ W2c[hid128][n]
#pragma unroll
    for (int ks = 0; ks < 4; ks++) {
      half8 a2 = *(const half8*)&hs[SW128(wa * 16 + l15, ks * 32 + quad * 8)];
      half8 bf[2];
#pragma unroll
      for (int nt = 0; nt < 2; nt++)
        bf[nt] = *(const half8*)&ws2[SW128(wb * 32 + nt * 16 + l15, ks * 32 + quad * 8)];
#pragma unroll
      for (int nt = 0; nt < 2; nt++)
        acc[nt] = __builtin_amdgcn_mfma_f32_16x16x32_f16(a2, bf[nt], acc[nt], 0, 0, 0);
    }
  }
  __syncthreads();  // last GEMM2 reads done; safe to alias ots over ws1/ws2
#pragma unroll
  for (int nt = 0; nt < 2; nt++)
#pragma unroll
    for (int r = 0; r < 4; r++)
      ots[(wa * 16 + quad * 4 + r) * 68 + wb * 32 + nt * 16 + l15] = acc[nt][r];
  __syncthreads();
  // residual + LN: 8 waves x 8 rows
  float* xo = (float*)x;
  for (int i = 0; i < 8; i++) {
    int row = wave * 8 + i;
    size_t off = (size_t)(r0 + row) * 64 + lane;
    float val = ots[row * 68 + lane] + xo[off];
    float sum = val;
#pragma unroll
    for (int o = 32; o > 0; o >>= 1) sum += __shfl_xor(sum, o);
    float mean = sum * (1.f / 64.f);
    float d = val - mean;
    float sq = d * d;
#pragma unroll
    for (int o = 32; o > 0; o >>= 1) sq += __shfl_xor(sq, o);
    xo[off] = d * rsqrtf(sq * (1.f / 64.f) + 1e-5f) * ln_s[lane] + ln_b[lane];
  }
}

// ---------------- head: out[B,V,3] = x[:, -1] @ W_head + b_head ----------------
__global__ __launch_bounds__(256) void k_head(
    const float* __restrict__ x, const float* __restrict__ Wh,
    const float* __restrict__ bh, float* __restrict__ out)
{
  int id = blockIdx.x * 256 + threadIdx.x;  // < B*V = 1024
  int b = id >> 6, v = id & 63;
  const float* xr = x + (size_t)(b * LL + (SS - 1) * VVV + v) * 64;
  float a0 = bh[0], a1 = bh[1], a2 = bh[2];
  for (int e = 0; e < 64; e++) {
    float xv = xr[e];
    a0 += xv * Wh[e * 3 + 0];
    a1 += xv * Wh[e * 3 + 1];
    a2 += xv * Wh[e * 3 + 2];
  }
  out[id * 3 + 0] = a0;
  out[id * 3 + 1] = a1;
  out[id * 3 + 2] = a2;
}

extern "C" void kernel_launch(void* const* d_in, const int* in_sizes, int n_in,
                              void* d_out, int out_size, void* d_ws, size_t ws_size,
                              hipStream_t stream) {
  const float* features = (const float*)d_in[0];
  const int*   ovtag    = (const int*)d_in[1];
  const int*   poiid    = (const int*)d_in[2];
  const float* W_raw    = (const float*)d_in[3];
  const float* b_raw    = (const float*)d_in[4];
  const float* pos_tab  = (const float*)d_in[5];
  const float* type_tab = (const float*)d_in[6];
  const float* poi_tab  = (const float*)d_in[7];
  const float* ov_tab   = (const float*)d_in[8];
  const float* W_comb   = (const float*)d_in[9];
  const float* b_comb   = (const float*)d_in[10];
  const float* Wqkv     = (const float*)d_in[11];
  const float* bqkv     = (const float*)d_in[12];
  const float* Wo       = (const float*)d_in[13];
  const float* bo       = (const float*)d_in[14];
  const float* ln1_s    = (const float*)d_in[15];
  const float* ln1_b    = (const float*)d_in[16];
  const float* W1       = (const float*)d_in[17];
  const float* b1       = (const float*)d_in[18];
  const float* W2       = (const float*)d_in[19];
  const float* b2       = (const float*)d_in[20];
  const float* ln2_s    = (const float*)d_in[21];
  const float* ln2_b    = (const float*)d_in[22];
  const float* W_head   = (const float*)d_in[23];
  const float* b_head   = (const float*)d_in[24];
  float* out = (float*)d_out;
  float* ws  = (float*)d_ws;

  float* zm   = ws;                        // BL
  float* x    = zm + BL;                   // BL*64
  float* qkvb = x + (size_t)BL * 64;       // BL*192
  float* obuf = qkvb + (size_t)BL * 192;   // BL*64

  _Float16* wcombt = (_Float16*)(obuf + (size_t)BL * 64);  // [64][80]
  _Float16* w1t    = wcombt + 8192;                        // [NL][2048][64]
  _Float16* w2t    = w1t + (size_t)NLAYER * PERL;          // [NL][64][2048]
  _Float16* wqkvt  = w2t + (size_t)NLAYER * PERL;          // [NL][192][64]
  _Float16* wot    = wqkvt + (size_t)NLAYER * 192 * 64;    // [NL][64][64]

  k_tr<<<dim3(1, 2, 1), 256, 0, stream>>>(W_comb, wcombt, 80, 64, 0, 0);
  k_tr<<<dim3(32, 1, 4), 256, 0, stream>>>(W1, w1t, 64, 2048, PERL, PERL);
  k_tr<<<dim3(1, 32, 4), 256, 0, stream>>>(W2, w2t, 2048, 64, PERL, PERL);
  k_tr<<<dim3(3, 1, 4), 256, 0, stream>>>(Wqkv, wqkvt, 64, 192, 64 * 192, 64 * 192);
  k_tr<<<dim3(1, 1, 4), 256, 0, stream>>>(Wo, wot, 64, 64, 64 * 64, 64 * 64);
  k_embcomb<<<256, 256, 0, stream>>>(features, ovtag, poiid, W_raw, b_raw,
                                     ov_tab, poi_tab, wcombt, b_comb,
                                     pos_tab, type_tab, x, zm);
  for (int l = 0; l < NLAYER; l++) {
    k_gemm16<<<dim3(256, 3), 256, 0, stream>>>(
        x, wqkvt + (size_t)l * 192 * 64, bqkv + l * 192, qkvb, 192);
    k_attn<<<512, 256, 0, stream>>>(qkvb, zm, obuf);
    k_oln<<<256, 256, 0, stream>>>(obuf, wot + (size_t)l * 64 * 64, bo + l * EE,
                                   x, ln1_s + l * EE, ln1_b + l * EE);
    k_ffn2<<<256, 512, 0, stream>>>(x, w1t + (size_t)l * PERL,
                                    w2t + (size_t)l * PERL, b1 + l * DFF_,
                                    b2 + l * EE, ln2_s + l * EE, ln2_b + l * EE);
  }
  k_head<<<4, 256, 0, stream>>>(x, W_head, b_head, out);
}

// Round 5
// 579.913 us; speedup vs baseline: 1.0602x; 1.0602x over previous
//
#include <hip/hip_runtime.h>
#include <math.h>

#define BB 16
#define SS 16
#define VVV 64
#define EE 64
#define HHH 8
#define NLAYER 4
#define DFF_ 2048
#define LL 1024   /* S*V */
#define BL 16384  /* B*L */
#define PERL 131072  /* 64*2048 elems per layer of W1 (and W2) */

typedef __attribute__((ext_vector_type(8))) _Float16 half8;
typedef __attribute__((ext_vector_type(4))) _Float16 half4v;
typedef __attribute__((ext_vector_type(4))) float f32x4;

// XOR-swizzled index into row-major fp16 LDS tiles with 64-half (128 B) rows —
// one bank wrap per row, 16B granules; measured conflict-free (rounds 2-3).
#define SW64(m, k)  (((m) << 6) + ((((k) >> 3) ^ ((m) & 7)) << 3) + ((k) & 7))

// ---------------- coalesced transpose + fp32->fp16: dst[c][r] = src[r][c] ----------------
__global__ __launch_bounds__(256) void k_tr(
    const float* __restrict__ src, _Float16* __restrict__ dst,
    int R, int C, long lsrc, long ldst)
{
  __shared__ float t[64][65];
  const float* s = src + (size_t)blockIdx.z * lsrc;
  _Float16* d = dst + (size_t)blockIdx.z * ldst;
  int c0 = blockIdx.x * 64, r0 = blockIdx.y * 64;
  int cc = threadIdx.x & 63, rr = threadIdx.x >> 6;
#pragma unroll
  for (int i = 0; i < 16; i++) {
    int r = i * 4 + rr;
    if (r0 + r < R && c0 + cc < C)
      t[r][cc] = s[(size_t)(r0 + r) * C + c0 + cc];
  }
  __syncthreads();
#pragma unroll
  for (int i = 0; i < 16; i++) {
    int c = i * 4 + rr;
    if (c0 + c < C && r0 + cc < R)
      d[(size_t)(c0 + c) * R + r0 + cc] = (_Float16)t[cc][c];
  }
}

// ------- fused embed + comb GEMM: x = concat@W_comb + b_comb + pos + type; also zm -------
__global__ __launch_bounds__(256) void k_embcomb(
    const float* __restrict__ features, const int* __restrict__ ovtag,
    const int* __restrict__ poiid, const float* __restrict__ W_raw,
    const float* __restrict__ b_raw, const float* __restrict__ ov_tab,
    const float* __restrict__ poi_tab, const _Float16* __restrict__ wcombt,
    const float* __restrict__ b_comb, const float* __restrict__ pos_tab,
    const float* __restrict__ type_tab, float* __restrict__ x,
    float* __restrict__ zm)
{
  constexpr int KP = 104;  // 96 + 8 halves pad
  __shared__ _Float16 As[64 * KP];
  __shared__ _Float16 Bs[64 * KP];
  int tid = threadIdx.x;
  int m0 = blockIdx.x * 64;
  int wave = tid >> 6, lane = tid & 63, quad = lane >> 4, l15 = lane & 15;
  int wm = wave >> 1, wn = wave & 1;
  // build concat tile directly in LDS (fp16)
  for (int p = tid; p < 1536; p += 256) {
    int r = p / 24, s = p - r * 24; int c = s * 4;
    int row = m0 + r;
    float f0 = features[row * 3 + 0];
    float f1 = features[row * 3 + 1];
    float f2 = features[row * 3 + 2];
    if (s == 0) zm[row] = ((f0 + f1 + f2) == 0.f) ? 1.f : 0.f;
    half4v h;
#pragma unroll
    for (int j = 0; j < 4; j++) {
      int cc = c + j; float v;
      if (cc < 64) {
        v = b_raw[cc] + f0 * W_raw[cc] + f1 * W_raw[64 + cc] + f2 * W_raw[128 + cc];
      } else if (cc < 72) {
        int t = ovtag[row]; v = (t <= 0) ? 0.f : ov_tab[t * 8 + cc - 64];
      } else if (cc < 80) {
        int t = poiid[row]; v = (t <= 0) ? 0.f : poi_tab[t * 8 + cc - 72];
      } else v = 0.f;
      h[j] = (_Float16)v;
    }
    *(half4v*)&As[r * KP + c] = h;
  }
  for (int p = tid; p < 1536; p += 256) {
    int r = p / 24, s = p - r * 24; int c = s * 4;
    half4v h = (half4v){0, 0, 0, 0};
    if (c < 80) h = *(const half4v*)&wcombt[r * 80 + c];
    *(half4v*)&Bs[r * KP + c] = h;
  }
  __syncthreads();
  f32x4 acc[2][2];
#pragma unroll
  for (int mt = 0; mt < 2; mt++)
#pragma unroll
    for (int nt = 0; nt < 2; nt++) {
      float bv = b_comb[wn * 32 + nt * 16 + l15];
      acc[mt][nt] = (f32x4){bv, bv, bv, bv};
    }
#pragma unroll
  for (int ks = 0; ks < 3; ks++) {
    half8 af[2], bf[2];
#pragma unroll
    for (int mt = 0; mt < 2; mt++)
      af[mt] = *(const half8*)&As[(wm * 32 + mt * 16 + l15) * KP + ks * 32 + quad * 8];
#pragma unroll
    for (int nt = 0; nt < 2; nt++)
      bf[nt] = *(const half8*)&Bs[(wn * 32 + nt * 16 + l15) * KP + ks * 32 + quad * 8];
#pragma unroll
    for (int mt = 0; mt < 2; mt++)
#pragma unroll
      for (int nt = 0; nt < 2; nt++)
        acc[mt][nt] = __builtin_amdgcn_mfma_f32_16x16x32_f16(af[mt], bf[nt],
                                                             acc[mt][nt], 0, 0, 0);
  }
#pragma unroll
  for (int mt = 0; mt < 2; mt++)
#pragma unroll
    for (int nt = 0; nt < 2; nt++)
#pragma unroll
      for (int r = 0; r < 4; r++) {
        int row = m0 + wm * 32 + mt * 16 + quad * 4 + r;
        int col = wn * 32 + nt * 16 + l15;
        int l = row & (LL - 1);
        x[(size_t)row * 64 + col] = acc[mt][nt][r] +
            pos_tab[(l >> 6) * 64 + col] + type_tab[(l & 63) * 64 + col];
      }
}

// ---------------- fp16 MFMA GEMM (QKV): C[M,N] = A[M,64]@Bt[N,64]^T + bias ----------------
__global__ __launch_bounds__(256) void k_gemm16(
    const float* __restrict__ A, const _Float16* __restrict__ Bt,
    const float* __restrict__ bias, float* __restrict__ C, int N)
{
  constexpr int KP = 72;
  __shared__ _Float16 As[64 * KP];
  __shared__ _Float16 Bs[64 * KP];
  int tid = threadIdx.x;
  int m0 = blockIdx.x * 64, n0 = blockIdx.y * 64;
  int wave = tid >> 6, lane = tid & 63, quad = lane >> 4, l15 = lane & 15;
  int wm = wave >> 1, wn = wave & 1;
  for (int p = tid; p < 1024; p += 256) {
    int r = p >> 4, c = (p & 15) << 2;
    float4 f = *(const float4*)&A[(size_t)(m0 + r) * 64 + c];
    *(half4v*)&As[r * KP + c] =
        (half4v){(_Float16)f.x, (_Float16)f.y, (_Float16)f.z, (_Float16)f.w};
  }
  for (int p = tid; p < 1024; p += 256) {
    int r = p >> 4, c = (p & 15) << 2;
    *(half4v*)&Bs[r * KP + c] = *(const half4v*)&Bt[(size_t)(n0 + r) * 64 + c];
  }
  __syncthreads();
  f32x4 acc[2][2];
#pragma unroll
  for (int mt = 0; mt < 2; mt++)
#pragma unroll
    for (int nt = 0; nt < 2; nt++) {
      float bv = bias[n0 + wn * 32 + nt * 16 + l15];
      acc[mt][nt] = (f32x4){bv, bv, bv, bv};
    }
#pragma unroll
  for (int ks = 0; ks < 2; ks++) {
    half8 af[2], bf[2];
#pragma unroll
    for (int mt = 0; mt < 2; mt++)
      af[mt] = *(const half8*)&As[(wm * 32 + mt * 16 + l15) * KP + ks * 32 + quad * 8];
#pragma unroll
    for (int nt = 0; nt < 2; nt++)
      bf[nt] = *(const half8*)&Bs[(wn * 32 + nt * 16 + l15) * KP + ks * 32 + quad * 8];
#pragma unroll
    for (int mt = 0; mt < 2; mt++)
#pragma unroll
      for (int nt = 0; nt < 2; nt++)
        acc[mt][nt] = __builtin_amdgcn_mfma_f32_16x16x32_f16(af[mt], bf[nt],
                                                             acc[mt][nt], 0, 0, 0);
  }
#pragma unroll
  for (int mt = 0; mt < 2; mt++)
#pragma unroll
    for (int nt = 0; nt < 2; nt++)
#pragma unroll
      for (int r = 0; r < 4; r++) {
        int row = m0 + wm * 32 + mt * 16 + quad * 4 + r;
        int col = n0 + wn * 32 + nt * 16 + l15;
        C[(size_t)row * N + col] = acc[mt][nt][r];
      }
}

// ---------------- attention: block = (b, h, 256 q-rows); masked online softmax ----------------
__global__ __launch_bounds__(256) void k_attn(
    const float* __restrict__ qkv, const float* __restrict__ zm,
    float* __restrict__ obuf)
{
  __shared__ float KsT[8 * 1024];
  __shared__ float VsT[8 * 1024];
  int blk = blockIdx.x;
  int qb = blk & 3, h = (blk >> 2) & 7, b = blk >> 5;
  const float* base = qkv + (size_t)b * LL * 192;
  for (int p = threadIdx.x; p < 8192; p += 256) {
    int k = p >> 3, d = p & 7;
    KsT[d * 1024 + k] = base[(size_t)k * 192 + 64 + h * 8 + d];
    VsT[d * 1024 + k] = base[(size_t)k * 192 + 128 + h * 8 + d];
  }
  __syncthreads();
  int qrow = qb * 256 + threadIdx.x;
  int tq = qrow >> 6, vq = qrow & 63;
  const float* zmb = zm + b * LL;
  float q[8];
#pragma unroll
  for (int d = 0; d < 8; d++) q[d] = base[(size_t)qrow * 192 + h * 8 + d];
  const float scale = 0.3535533905932738f;
  float m = -INFINITY, lsum = 0.f;
  float acc[8] = {0.f, 0.f, 0.f, 0.f, 0.f, 0.f, 0.f, 0.f};
  bool zmq = (zmb[qrow] != 0.f);

  auto attend = [&](int k) {
    if (zmb[k] != 0.f) return;
    float s = 0.f;
#pragma unroll
    for (int d = 0; d < 8; d++) s += q[d] * KsT[d * 1024 + k];
    s *= scale;
    if (s <= m) {
      float p = __expf(s - m);
      lsum += p;
#pragma unroll
      for (int d = 0; d < 8; d++) acc[d] += p * VsT[d * 1024 + k];
    } else {
      float r = __expf(m - s);
      lsum = lsum * r + 1.f;
#pragma unroll
      for (int d = 0; d < 8; d++) acc[d] = acc[d] * r + VsT[d * 1024 + k];
      m = s;
    }
  };

  if (!zmq) {
    for (int vv = 0; vv < 64; vv++) attend(tq * 64 + vv);
    for (int tt = 0; tt < 16; tt++) {
      if (tt == tq) continue;
      attend(tt * 64 + vq);
    }
  }
  float inv = 1.f / lsum;
  float* orow = obuf + (size_t)(b * LL + qrow) * 64 + h * 8;
#pragma unroll
  for (int d = 0; d < 8; d++) orow[d] = acc[d] * inv;
}

// ---------------- fused o-proj + residual + LN1: x = LN(x + o@Wo + bo) ----------------
__global__ __launch_bounds__(256) void k_oln(
    const float* __restrict__ obuf, const _Float16* __restrict__ wot,
    const float* __restrict__ bo, float* __restrict__ x,
    const float* __restrict__ ln_s, const float* __restrict__ ln_b)
{
  constexpr int KP = 72;
  __shared__ _Float16 As[64 * KP];
  __shared__ _Float16 Bs[64 * KP];
  __shared__ float ots[64 * 68];
  int tid = threadIdx.x;
  int m0 = blockIdx.x * 64;
  int wave = tid >> 6, lane = tid & 63, quad = lane >> 4, l15 = lane & 15;
  int wm = wave >> 1, wn = wave & 1;
  for (int p = tid; p < 1024; p += 256) {
    int r = p >> 4, c = (p & 15) << 2;
    float4 f = *(const float4*)&obuf[(size_t)(m0 + r) * 64 + c];
    *(half4v*)&As[r * KP + c] =
        (half4v){(_Float16)f.x, (_Float16)f.y, (_Float16)f.z, (_Float16)f.w};
  }
  for (int p = tid; p < 1024; p += 256) {
    int r = p >> 4, c = (p & 15) << 2;
    *(half4v*)&Bs[r * KP + c] = *(const half4v*)&wot[(size_t)r * 64 + c];
  }
  __syncthreads();
  f32x4 acc[2][2];
#pragma unroll
  for (int mt = 0; mt < 2; mt++)
#pragma unroll
    for (int nt = 0; nt < 2; nt++) {
      float bv = bo[wn * 32 + nt * 16 + l15];
      acc[mt][nt] = (f32x4){bv, bv, bv, bv};
    }
#pragma unroll
  for (int ks = 0; ks < 2; ks++) {
    half8 af[2], bf[2];
#pragma unroll
    for (int mt = 0; mt < 2; mt++)
      af[mt] = *(const half8*)&As[(wm * 32 + mt * 16 + l15) * KP + ks * 32 + quad * 8];
#pragma unroll
    for (int nt = 0; nt < 2; nt++)
      bf[nt] = *(const half8*)&Bs[(wn * 32 + nt * 16 + l15) * KP + ks * 32 + quad * 8];
#pragma unroll
    for (int mt = 0; mt < 2; mt++)
#pragma unroll
      for (int nt = 0; nt < 2; nt++)
        acc[mt][nt] = __builtin_amdgcn_mfma_f32_16x16x32_f16(af[mt], bf[nt],
                                                             acc[mt][nt], 0, 0, 0);
  }
#pragma unroll
  for (int mt = 0; mt < 2; mt++)
#pragma unroll
    for (int nt = 0; nt < 2; nt++)
#pragma unroll
      for (int r = 0; r < 4; r++)
        ots[(wm * 32 + mt * 16 + quad * 4 + r) * 68 + wn * 32 + nt * 16 + l15] =
            acc[mt][nt][r];
  __syncthreads();
  // LN: 4 waves x 16 rows, lane = dim
  for (int i = 0; i < 16; i++) {
    int row = wave * 16 + i;
    size_t off = (size_t)(m0 + row) * 64 + lane;
    float val = ots[row * 68 + lane] + x[off];
    float sum = val;
#pragma unroll
    for (int o = 32; o > 0; o >>= 1) sum += __shfl_xor(sum, o);
    float mean = sum * (1.f / 64.f);
    float d = val - mean;
    float sq = d * d;
#pragma unroll
    for (int o = 32; o > 0; o >>= 1) sq += __shfl_xor(sq, o);
    x[off] = d * rsqrtf(sq * (1.f / 64.f) + 1e-5f) * ln_s[lane] + ln_b[lane];
  }
}

// -------- FFN fp16 MFMA: out_part[split] = relu(x@W1[:,rng]+b1)@W2[rng,:] (+b2 if s0) ----
// grid (256, 2): 512 blocks = 2/CU. 128-wide hidden chunks, 8 iters, all-SW64 tiles.
__global__ __launch_bounds__(256) void k_ffn3(
    const float* __restrict__ x, const _Float16* __restrict__ w1t,
    const _Float16* __restrict__ w2t, const float* __restrict__ b1,
    const float* __restrict__ b2, float* __restrict__ out)
{
  __shared__ _Float16 ws1[8192];      // 128 hid rows x 64 k (SW64 rows) — 16 KB
  __shared__ _Float16 ws2[2][4096];   // 2 x (64 n rows x 64 h)           — 16 KB
  __shared__ _Float16 hs[2][4096];    // 2 x (64 m rows x 64 h)           — 16 KB
  int tid = threadIdx.x;
  int r0 = blockIdx.x * 64;
  int split = blockIdx.y;             // hidden range [split*1024, +1024)
  int wave = tid >> 6, lane = tid & 63;
  int quad = lane >> 4, l15 = lane & 15;
  int wa = wave >> 1, wb = wave & 1;

  const _Float16* w1g = w1t + (size_t)split * 1024 * 64;
  const float* b1g = b1 + split * 1024;

  // x B-fragments for GEMM1^T, loaded once from global (rows m = wb*32+mt*16+l15)
  half8 xb[2][2];
#pragma unroll
  for (int mt = 0; mt < 2; mt++)
#pragma unroll
    for (int ks = 0; ks < 2; ks++) {
      const float* xr = x + (size_t)(r0 + wb * 32 + mt * 16 + l15) * 64 +
                        ks * 32 + quad * 8;
      float4 f0 = *(const float4*)xr;
      float4 f1 = *(const float4*)(xr + 4);
      xb[mt][ks] = (half8){(_Float16)f0.x, (_Float16)f0.y, (_Float16)f0.z,
                           (_Float16)f0.w, (_Float16)f1.x, (_Float16)f1.y,
                           (_Float16)f1.z, (_Float16)f1.w};
    }

  // GEMM2 acc: row m = wa*32+mt*16+quad*4+r, col n = wb*32+nt*16+l15
  f32x4 acc[2][2];
#pragma unroll
  for (int mt = 0; mt < 2; mt++)
#pragma unroll
    for (int nt = 0; nt < 2; nt++) {
      float bv = (split == 0) ? b2[wb * 32 + nt * 16 + l15] : 0.f;
      acc[mt][nt] = (f32x4){bv, bv, bv, bv};
    }

  for (int i = 0; i < 8; i++) {
    int hb = i * 128;   // chunk base within this split's 1024
    __syncthreads();    // prev iter's reads of ws1/ws2/hs done
    // stage W1 chunk (128 rows x 64 k, contiguous) and W2 slice (64 n x 128 h)
    for (int p = tid; p < 2048; p += 256) {
      int r = p >> 4, s = (p & 15) << 2;
      *(half4v*)&ws1[SW64(r, s)] = *(const half4v*)&w1g[(size_t)(hb + r) * 64 + s];
    }
    for (int p = tid; p < 2048; p += 256) {
      int n = p >> 5, c = (p & 31) << 2;   // c in [0,128)
      *(half4v*)&ws2[c >> 6][SW64(n, c & 63)] =
          *(const half4v*)&w2t[(size_t)n * 2048 + split * 1024 + hb + c];
    }
    __syncthreads();
    // GEMM1^T: Ht[h 128][m 64]; wave: h-half = wa (64), m-half = wb (32)
#pragma unroll
    for (int ht = 0; ht < 4; ht++) {
      f32x4 hacc[2] = {(f32x4){0.f, 0.f, 0.f, 0.f}, (f32x4){0.f, 0.f, 0.f, 0.f}};
#pragma unroll
      for (int ks = 0; ks < 2; ks++) {
        half8 a1 = *(const half8*)&ws1[SW64(wa * 64 + ht * 16 + l15,
                                            ks * 32 + quad * 8)];
#pragma unroll
        for (int mt = 0; mt < 2; mt++)
          hacc[mt] = __builtin_amdgcn_mfma_f32_16x16x32_f16(a1, xb[mt][ks],
                                                            hacc[mt], 0, 0, 0);
      }
      // bias + relu + pack: lane holds h = wa*64+ht*16+quad*4..+4, m = wb*32+mt*16+l15
      float4 bb = *(const float4*)&b1g[hb + wa * 64 + ht * 16 + quad * 4];
#pragma unroll
      for (int mt = 0; mt < 2; mt++) {
        f32x4 h = hacc[mt];
        half4v hp = (half4v){
            (_Float16)fmaxf(h[0] + bb.x, 0.f), (_Float16)fmaxf(h[1] + bb.y, 0.f),
            (_Float16)fmaxf(h[2] + bb.z, 0.f), (_Float16)fmaxf(h[3] + bb.w, 0.f)};
        *(half4v*)&hs[wa][SW64(wb * 32 + mt * 16 + l15, ht * 16 + quad * 4)] = hp;
      }
    }
    __syncthreads();  // hs visible
    // GEMM2: acc += H[m][h128] @ W2c[h128][n]; wave: m-half = wa, n-half = wb
#pragma unroll
    for (int ks = 0; ks < 4; ks++) {
      int kt = ks >> 1, kh = (ks & 1) * 32 + quad * 8;
      half8 a2[2], bf[2];
#pragma unroll
      for (int mt = 0; mt < 2; mt++)
        a2[mt] = *(const half8*)&hs[kt][SW64(wa * 32 + mt * 16 + l15, kh)];
#pragma unroll
      for (int nt = 0; nt < 2; nt++)
        bf[nt] = *(const half8*)&ws2[kt][SW64(wb * 32 + nt * 16 + l15, kh)];
#pragma unroll
      for (int mt = 0; mt < 2; mt++)
#pragma unroll
        for (int nt = 0; nt < 2; nt++)
          acc[mt][nt] = __builtin_amdgcn_mfma_f32_16x16x32_f16(a2[mt], bf[nt],
                                                               acc[mt][nt], 0, 0, 0);
    }
  }
#pragma unroll
  for (int mt = 0; mt < 2; mt++)
#pragma unroll
    for (int nt = 0; nt < 2; nt++)
#pragma unroll
      for (int r = 0; r < 4; r++) {
        int row = r0 + wa * 32 + mt * 16 + quad * 4 + r;
        int col = wb * 32 + nt * 16 + l15;
        out[(size_t)split * ((size_t)BL * 64) + (size_t)row * 64 + col] =
            acc[mt][nt][r];
      }
}

// ---------------- residual + LayerNorm (wave per row), in-place on x ----------------
__global__ __launch_bounds__(256) void k_resln(
    float* __restrict__ x, const float* __restrict__ tmp, int nparts,
    const float* __restrict__ sc, const float* __restrict__ bs)
{
  int lane = threadIdx.x & 63;
  int row = blockIdx.x * 4 + (threadIdx.x >> 6);
  size_t off = (size_t)row * 64 + lane;
  float val = x[off];
  for (int p = 0; p < nparts; p++) val += tmp[(size_t)p * ((size_t)BL * 64) + off];
  float sum = val;
#pragma unroll
  for (int o = 32; o > 0; o >>= 1) sum += __shfl_xor(sum, o);
  float mean = sum * (1.f / 64.f);
  float d = val - mean;
  float sq = d * d;
#pragma unroll
  for (int o = 32; o > 0; o >>= 1) sq += __shfl_xor(sq, o);
  float var = sq * (1.f / 64.f);
  x[off] = d * rsqrtf(var + 1e-5f) * sc[lane] + bs[lane];
}

// ---------------- head: out[B,V,3] = x[:, -1] @ W_head + b_head ----------------
__global__ __launch_bounds__(256) void k_head(
    const float* __restrict__ x, const float* __restrict__ Wh,
    const float* __restrict__ bh, float* __restrict__ out)
{
  int id = blockIdx.x * 256 + threadIdx.x;  // < B*V = 1024
  int b = id >> 6, v = id & 63;
  const float* xr = x + (size_t)(b * LL + (SS - 1) * VVV + v) * 64;
  float a0 = bh[0], a1 = bh[1], a2 = bh[2];
  for (int e = 0; e < 64; e++) {
    float xv = xr[e];
    a0 += xv * Wh[e * 3 + 0];
    a1 += xv * Wh[e * 3 + 1];
    a2 += xv * Wh[e * 3 + 2];
  }
  out[id * 3 + 0] = a0;
  out[id * 3 + 1] = a1;
  out[id * 3 + 2] = a2;
}

extern "C" void kernel_launch(void* const* d_in, const int* in_sizes, int n_in,
                              void* d_out, int out_size, void* d_ws, size_t ws_size,
                              hipStream_t stream) {
  const float* features = (const float*)d_in[0];
  const int*   ovtag    = (const int*)d_in[1];
  const int*   poiid    = (const int*)d_in[2];
  const float* W_raw    = (const float*)d_in[3];
  const float* b_raw    = (const float*)d_in[4];
  const float* pos_tab  = (const float*)d_in[5];
  const float* type_tab = (const float*)d_in[6];
  const float* poi_tab  = (const float*)d_in[7];
  const float* ov_tab   = (const float*)d_in[8];
  const float* W_comb   = (const float*)d_in[9];
  const float* b_comb   = (const float*)d_in[10];
  const float* Wqkv     = (const float*)d_in[11];
  const float* bqkv     = (const float*)d_in[12];
  const float* Wo       = (const float*)d_in[13];
  const float* bo       = (const float*)d_in[14];
  const float* ln1_s    = (const float*)d_in[15];
  const float* ln1_b    = (const float*)d_in[16];
  const float* W1       = (const float*)d_in[17];
  const float* b1       = (const float*)d_in[18];
  const float* W2       = (const float*)d_in[19];
  const float* b2       = (const float*)d_in[20];
  const float* ln2_s    = (const float*)d_in[21];
  const float* ln2_b    = (const float*)d_in[22];
  const float* W_head   = (const float*)d_in[23];
  const float* b_head   = (const float*)d_in[24];
  float* out = (float*)d_out;
  float* ws  = (float*)d_ws;

  float* zm   = ws;                        // BL
  float* x    = zm + BL;                   // BL*64
  float* qkvb = x + (size_t)BL * 64;       // BL*192
  float* obuf = qkvb + (size_t)BL * 192;   // BL*64
  float* tmp  = obuf + (size_t)BL * 64;    // 2 * BL*64

  _Float16* wcombt = (_Float16*)(tmp + 2 * (size_t)BL * 64);  // [64][80]
  _Float16* w1t    = wcombt + 8192;                        // [NL][2048][64]
  _Float16* w2t    = w1t + (size_t)NLAYER * PERL;          // [NL][64][2048]
  _Float16* wqkvt  = w2t + (size_t)NLAYER * PERL;          // [NL][192][64]
  _Float16* wot    = wqkvt + (size_t)NLAYER * 192 * 64;    // [NL][64][64]

  k_tr<<<dim3(1, 2, 1), 256, 0, stream>>>(W_comb, wcombt, 80, 64, 0, 0);
  k_tr<<<dim3(32, 1, 4), 256, 0, stream>>>(W1, w1t, 64, 2048, PERL, PERL);
  k_tr<<<dim3(1, 32, 4), 256, 0, stream>>>(W2, w2t, 2048, 64, PERL, PERL);
  k_tr<<<dim3(3, 1, 4), 256, 0, stream>>>(Wqkv, wqkvt, 64, 192, 64 * 192, 64 * 192);
  k_tr<<<dim3(1, 1, 4), 256, 0, stream>>>(Wo, wot, 64, 64, 64 * 64, 64 * 64);
  k_embcomb<<<256, 256, 0, stream>>>(features, ovtag, poiid, W_raw, b_raw,
                                     ov_tab, poi_tab, wcombt, b_comb,
                                     pos_tab, type_tab, x, zm);
  for (int l = 0; l < NLAYER; l++) {
    k_gemm16<<<dim3(256, 3), 256, 0, stream>>>(
        x, wqkvt + (size_t)l * 192 * 64, bqkv + l * 192, qkvb, 192);
    k_attn<<<512, 256, 0, stream>>>(qkvb, zm, obuf);
    k_oln<<<256, 256, 0, stream>>>(obuf, wot + (size_t)l * 64 * 64, bo + l * EE,
                                   x, ln1_s + l * EE, ln1_b + l * EE);
    k_ffn3<<<dim3(256, 2), 256, 0, stream>>>(
        x, w1t + (size_t)l * PERL, w2t + (size_t)l * PERL,
        b1 + l * DFF_, b2 + l * EE, tmp);
    k_resln<<<BL / 4, 256, 0, stream>>>(x, tmp, 2, ln2_s + l * EE, ln2_b + l * EE);
  }
  k_head<<<4, 256, 0, stream>>>(x, W_head, b_head, out);
}

// Round 6
// 459.494 us; speedup vs baseline: 1.3381x; 1.2621x over previous
//
#include <hip/hip_runtime.h>
#include <math.h>

#define BB 16
#define SS 16
#define VVV 64
#define EE 64
#define HHH 8
#define NLAYER 4
#define DFF_ 2048
#define LL 1024   /* S*V */
#define BL 16384  /* B*L */
#define PERL 131072  /* 64*2048 elems per layer of W1 (and W2) */

typedef __attribute__((ext_vector_type(8))) _Float16 half8;
typedef __attribute__((ext_vector_type(4))) _Float16 half4v;
typedef __attribute__((ext_vector_type(2))) _Float16 half2v;
typedef __attribute__((ext_vector_type(4))) float f32x4;

#if defined(__has_builtin)
#if __has_builtin(__builtin_amdgcn_fdot2)
#define HAVE_FDOT2 1
#endif
#endif

// XOR-swizzled index into row-major fp16 LDS tiles with 64-half (128 B) rows —
// one bank wrap per row; 2-way max aliasing (free per m136).
#define SW64(m, k)  (((m) << 6) + ((((k) >> 3) ^ ((m) & 7)) << 3) + ((k) & 7))

// ---------------- merged prep: all weight transposes fp32->fp16 in ONE dispatch ----------
__global__ __launch_bounds__(256) void k_prep(
    const float* __restrict__ W1, const float* __restrict__ W2,
    const float* __restrict__ Wqkv, const float* __restrict__ Wo,
    const float* __restrict__ Wcomb,
    _Float16* __restrict__ w1t, _Float16* __restrict__ w2t,
    _Float16* __restrict__ wqkvt, _Float16* __restrict__ wot,
    _Float16* __restrict__ wcombt)
{
  int b = blockIdx.x;
  const float* src; _Float16* dst; int R, C, r0, c0;
  if (b < 128) {        // W1 [64][2048] -> w1t [2048][64]
    int l = b >> 5, ct = b & 31;
    src = W1 + (size_t)l * PERL; dst = w1t + (size_t)l * PERL;
    R = 64; C = 2048; r0 = 0; c0 = ct * 64;
  } else if (b < 256) { // W2 [2048][64] -> w2t [64][2048]
    int j = b - 128; int l = j >> 5, rt = j & 31;
    src = W2 + (size_t)l * PERL; dst = w2t + (size_t)l * PERL;
    R = 2048; C = 64; r0 = rt * 64; c0 = 0;
  } else if (b < 268) { // Wqkv [64][192] -> wqkvt [192][64]
    int j = b - 256; int l = j / 3, ct = j % 3;
    src = Wqkv + (size_t)l * 64 * 192; dst = wqkvt + (size_t)l * 192 * 64;
    R = 64; C = 192; r0 = 0; c0 = ct * 64;
  } else if (b < 272) { // Wo [64][64] -> wot [64][64]^T
    int l = b - 268;
    src = Wo + (size_t)l * 4096; dst = wot + (size_t)l * 4096;
    R = 64; C = 64; r0 = 0; c0 = 0;
  } else {              // Wcomb [80][64] -> wcombt [64][80]
    int rt = b - 272;
    src = Wcomb; dst = wcombt;
    R = 80; C = 64; r0 = rt * 64; c0 = 0;
  }
  __shared__ float t[64][65];
  int cc = threadIdx.x & 63, rr = threadIdx.x >> 6;
#pragma unroll
  for (int i = 0; i < 16; i++) {
    int r = i * 4 + rr;
    if (r0 + r < R && c0 + cc < C)
      t[r][cc] = src[(size_t)(r0 + r) * C + c0 + cc];
  }
  __syncthreads();
#pragma unroll
  for (int i = 0; i < 16; i++) {
    int c = i * 4 + rr;
    if (c0 + c < C && r0 + cc < R)
      dst[(size_t)(c0 + c) * R + r0 + cc] = (_Float16)t[cc][c];
  }
}

// ------- fused embed + comb GEMM: x = concat@W_comb + b_comb + pos + type; also zm -------
__global__ __launch_bounds__(256) void k_embcomb(
    const float* __restrict__ features, const int* __restrict__ ovtag,
    const int* __restrict__ poiid, const float* __restrict__ W_raw,
    const float* __restrict__ b_raw, const float* __restrict__ ov_tab,
    const float* __restrict__ poi_tab, const _Float16* __restrict__ wcombt,
    const float* __restrict__ b_comb, const float* __restrict__ pos_tab,
    const float* __restrict__ type_tab, float* __restrict__ x,
    float* __restrict__ zm)
{
  constexpr int KP = 104;
  __shared__ _Float16 As[64 * KP];
  __shared__ _Float16 Bs[64 * KP];
  int tid = threadIdx.x;
  int m0 = blockIdx.x * 64;
  int wave = tid >> 6, lane = tid & 63, quad = lane >> 4, l15 = lane & 15;
  int wm = wave >> 1, wn = wave & 1;
  for (int p = tid; p < 1536; p += 256) {
    int r = p / 24, s = p - r * 24; int c = s * 4;
    int row = m0 + r;
    float f0 = features[row * 3 + 0];
    float f1 = features[row * 3 + 1];
    float f2 = features[row * 3 + 2];
    if (s == 0) zm[row] = ((f0 + f1 + f2) == 0.f) ? 1.f : 0.f;
    half4v h;
#pragma unroll
    for (int j = 0; j < 4; j++) {
      int cc = c + j; float v;
      if (cc < 64) {
        v = b_raw[cc] + f0 * W_raw[cc] + f1 * W_raw[64 + cc] + f2 * W_raw[128 + cc];
      } else if (cc < 72) {
        int t = ovtag[row]; v = (t <= 0) ? 0.f : ov_tab[t * 8 + cc - 64];
      } else if (cc < 80) {
        int t = poiid[row]; v = (t <= 0) ? 0.f : poi_tab[t * 8 + cc - 72];
      } else v = 0.f;
      h[j] = (_Float16)v;
    }
    *(half4v*)&As[r * KP + c] = h;
  }
  for (int p = tid; p < 1536; p += 256) {
    int r = p / 24, s = p - r * 24; int c = s * 4;
    half4v h = (half4v){0, 0, 0, 0};
    if (c < 80) h = *(const half4v*)&wcombt[r * 80 + c];
    *(half4v*)&Bs[r * KP + c] = h;
  }
  __syncthreads();
  f32x4 acc[2][2];
#pragma unroll
  for (int mt = 0; mt < 2; mt++)
#pragma unroll
    for (int nt = 0; nt < 2; nt++) {
      float bv = b_comb[wn * 32 + nt * 16 + l15];
      acc[mt][nt] = (f32x4){bv, bv, bv, bv};
    }
#pragma unroll
  for (int ks = 0; ks < 3; ks++) {
    half8 af[2], bf[2];
#pragma unroll
    for (int mt = 0; mt < 2; mt++)
      af[mt] = *(const half8*)&As[(wm * 32 + mt * 16 + l15) * KP + ks * 32 + quad * 8];
#pragma unroll
    for (int nt = 0; nt < 2; nt++)
      bf[nt] = *(const half8*)&Bs[(wn * 32 + nt * 16 + l15) * KP + ks * 32 + quad * 8];
#pragma unroll
    for (int mt = 0; mt < 2; mt++)
#pragma unroll
      for (int nt = 0; nt < 2; nt++)
        acc[mt][nt] = __builtin_amdgcn_mfma_f32_16x16x32_f16(af[mt], bf[nt],
                                                             acc[mt][nt], 0, 0, 0);
  }
#pragma unroll
  for (int mt = 0; mt < 2; mt++)
#pragma unroll
    for (int nt = 0; nt < 2; nt++)
#pragma unroll
      for (int r = 0; r < 4; r++) {
        int row = m0 + wm * 32 + mt * 16 + quad * 4 + r;
        int col = wn * 32 + nt * 16 + l15;
        int l = row & (LL - 1);
        x[(size_t)row * 64 + col] = acc[mt][nt][r] +
            pos_tab[(l >> 6) * 64 + col] + type_tab[(l & 63) * 64 + col];
      }
}

// ---- QKV GEMM, zero LDS / zero barriers: frags direct from global; fp16 out ----
__global__ __launch_bounds__(256) void k_qkv(
    const float* __restrict__ x, const _Float16* __restrict__ bt,
    const float* __restrict__ bias, _Float16* __restrict__ outq)
{
  int tid = threadIdx.x;
  int m0 = blockIdx.x * 64, n0 = blockIdx.y * 64;
  int wave = tid >> 6, lane = tid & 63, quad = lane >> 4, l15 = lane & 15;
  int wm = wave >> 1, wn = wave & 1;
  half8 af[2][2], bf[2][2];
#pragma unroll
  for (int mt = 0; mt < 2; mt++)
#pragma unroll
    for (int ks = 0; ks < 2; ks++) {
      const float* xr = &x[(size_t)(m0 + wm * 32 + mt * 16 + l15) * 64 +
                           ks * 32 + quad * 8];
      float4 f0 = *(const float4*)xr;
      float4 f1 = *(const float4*)(xr + 4);
      af[mt][ks] = (half8){(_Float16)f0.x, (_Float16)f0.y, (_Float16)f0.z,
                           (_Float16)f0.w, (_Float16)f1.x, (_Float16)f1.y,
                           (_Float16)f1.z, (_Float16)f1.w};
    }
#pragma unroll
  for (int nt = 0; nt < 2; nt++)
#pragma unroll
    for (int ks = 0; ks < 2; ks++)
      bf[nt][ks] = *(const half8*)&bt[(size_t)(n0 + wn * 32 + nt * 16 + l15) * 64 +
                                      ks * 32 + quad * 8];
  f32x4 acc[2][2];
#pragma unroll
  for (int mt = 0; mt < 2; mt++)
#pragma unroll
    for (int nt = 0; nt < 2; nt++) {
      float bv = bias[n0 + wn * 32 + nt * 16 + l15];
      acc[mt][nt] = (f32x4){bv, bv, bv, bv};
    }
#pragma unroll
  for (int ks = 0; ks < 2; ks++)
#pragma unroll
    for (int mt = 0; mt < 2; mt++)
#pragma unroll
      for (int nt = 0; nt < 2; nt++)
        acc[mt][nt] = __builtin_amdgcn_mfma_f32_16x16x32_f16(af[mt][ks], bf[nt][ks],
                                                             acc[mt][nt], 0, 0, 0);
#pragma unroll
  for (int mt = 0; mt < 2; mt++)
#pragma unroll
    for (int nt = 0; nt < 2; nt++)
#pragma unroll
      for (int r = 0; r < 4; r++) {
        int row = m0 + wm * 32 + mt * 16 + quad * 4 + r;
        int col = n0 + wn * 32 + nt * 16 + l15;
        outq[(size_t)row * 192 + col] = (_Float16)acc[mt][nt][r];
      }
}

// ---------------- attention: fp16 K/V in [k][d] LDS; masked online softmax ----------------
__global__ __launch_bounds__(256) void k_attn2(
    const _Float16* __restrict__ qkv, const float* __restrict__ zm,
    _Float16* __restrict__ obuf)
{
  __shared__ _Float16 Ks[1024 * 8];   // 16 KB
  __shared__ _Float16 Vs[1024 * 8];   // 16 KB
  __shared__ float zs[1024];          // 4 KB
  int blk = blockIdx.x;
  int qb = blk & 3, h = (blk >> 2) & 7, b = blk >> 5;
  const _Float16* base = qkv + (size_t)b * LL * 192;
  for (int p = threadIdx.x; p < 1024; p += 256) {
    *(half8*)&Ks[p * 8] = *(const half8*)&base[(size_t)p * 192 + 64 + h * 8];
    *(half8*)&Vs[p * 8] = *(const half8*)&base[(size_t)p * 192 + 128 + h * 8];
    zs[p] = zm[b * LL + p];
  }
  __syncthreads();
  int qrow = qb * 256 + threadIdx.x;
  int tq = qrow >> 6, vq = qrow & 63;
  half8 qh = *(const half8*)&base[(size_t)qrow * 192 + h * 8];
  const float scale = 0.3535533905932738f;
  float m = -INFINITY, lsum = 0.f;
  float acc[8] = {0.f, 0.f, 0.f, 0.f, 0.f, 0.f, 0.f, 0.f};
  bool zmq = (zs[qrow] != 0.f);

  auto attend = [&](int k) {
    if (zs[k] != 0.f) return;
    half8 kk = *(const half8*)&Ks[k * 8];
    float s = 0.f;
#ifdef HAVE_FDOT2
#pragma unroll
    for (int j = 0; j < 4; j++) {
      half2v qa = (half2v){qh[2 * j], qh[2 * j + 1]};
      half2v ka = (half2v){kk[2 * j], kk[2 * j + 1]};
      s = __builtin_amdgcn_fdot2(qa, ka, s, false);
    }
#else
#pragma unroll
    for (int j = 0; j < 8; j++) s += (float)qh[j] * (float)kk[j];
#endif
    s *= scale;
    half8 vv = *(const half8*)&Vs[k * 8];
    if (s <= m) {
      float p = __expf(s - m);
      lsum += p;
#pragma unroll
      for (int d = 0; d < 8; d++) acc[d] += p * (float)vv[d];
    } else {
      float r = __expf(m - s);
      lsum = lsum * r + 1.f;
#pragma unroll
      for (int d = 0; d < 8; d++) acc[d] = acc[d] * r + (float)vv[d];
      m = s;
    }
  };

  if (!zmq) {
    for (int vv = 0; vv < 64; vv++) attend(tq * 64 + vv);   // wave-uniform k
    for (int tt = 0; tt < 16; tt++) {
      if (tt == tq) continue;
      attend(tt * 64 + vq);
    }
  }
  float inv = 1.f / lsum;
  half8 o;
#pragma unroll
  for (int d = 0; d < 8; d++) o[d] = (_Float16)(acc[d] * inv);
  *(half8*)&obuf[(size_t)(b * LL + qrow) * 64 + h * 8] = o;
}

// ---- fused o-proj + residual + LN1: frags direct from global (fp16 obuf); 1 barrier ----
__global__ __launch_bounds__(256) void k_oln2(
    const _Float16* __restrict__ obuf, const _Float16* __restrict__ wot,
    const float* __restrict__ bo, float* __restrict__ x,
    const float* __restrict__ ln_s, const float* __restrict__ ln_b)
{
  __shared__ float ots[64 * 68];
  int tid = threadIdx.x;
  int m0 = blockIdx.x * 64;
  int wave = tid >> 6, lane = tid & 63, quad = lane >> 4, l15 = lane & 15;
  int wm = wave >> 1, wn = wave & 1;
  half8 af[2][2], bf[2][2];
#pragma unroll
  for (int mt = 0; mt < 2; mt++)
#pragma unroll
    for (int ks = 0; ks < 2; ks++)
      af[mt][ks] = *(const half8*)&obuf[(size_t)(m0 + wm * 32 + mt * 16 + l15) * 64 +
                                        ks * 32 + quad * 8];
#pragma unroll
  for (int nt = 0; nt < 2; nt++)
#pragma unroll
    for (int ks = 0; ks < 2; ks++)
      bf[nt][ks] = *(const half8*)&wot[(size_t)(wn * 32 + nt * 16 + l15) * 64 +
                                       ks * 32 + quad * 8];
  f32x4 acc[2][2];
#pragma unroll
  for (int mt = 0; mt < 2; mt++)
#pragma unroll
    for (int nt = 0; nt < 2; nt++) {
      float bv = bo[wn * 32 + nt * 16 + l15];
      acc[mt][nt] = (f32x4){bv, bv, bv, bv};
    }
#pragma unroll
  for (int ks = 0; ks < 2; ks++)
#pragma unroll
    for (int mt = 0; mt < 2; mt++)
#pragma unroll
      for (int nt = 0; nt < 2; nt++)
        acc[mt][nt] = __builtin_amdgcn_mfma_f32_16x16x32_f16(af[mt][ks], bf[nt][ks],
                                                             acc[mt][nt], 0, 0, 0);
#pragma unroll
  for (int mt = 0; mt < 2; mt++)
#pragma unroll
    for (int nt = 0; nt < 2; nt++)
#pragma unroll
      for (int r = 0; r < 4; r++)
        ots[(wm * 32 + mt * 16 + quad * 4 + r) * 68 + wn * 32 + nt * 16 + l15] =
            acc[mt][nt][r];
  __syncthreads();
  for (int i = 0; i < 16; i++) {
    int row = wave * 16 + i;
    size_t off = (size_t)(m0 + row) * 64 + lane;
    float val = ots[row * 68 + lane] + x[off];
    float sum = val;
#pragma unroll
    for (int o = 32; o > 0; o >>= 1) sum += __shfl_xor(sum, o);
    float mean = sum * (1.f / 64.f);
    float d = val - mean;
    float sq = d * d;
#pragma unroll
    for (int o = 32; o > 0; o >>= 1) sq += __shfl_xor(sq, o);
    x[off] = d * rsqrtf(sq * (1.f / 64.f) + 1e-5f) * ln_s[lane] + ln_b[lane];
  }
}

// ---- FFN: weights global->VGPR frags (no weight LDS); dbuf H tile; 1 barrier/chunk ----
// grid (256, 4): split s covers hidden [s*512, s*512+512), 8 chunks of 64.
__global__ __launch_bounds__(256) void k_ffn4(
    const float* __restrict__ x, const _Float16* __restrict__ w1t,
    const _Float16* __restrict__ w2t, const float* __restrict__ b1,
    const float* __restrict__ b2, float* __restrict__ out)
{
  __shared__ _Float16 hs[2][4096];   // dbuf 64m x 64h SW64 — 16 KB total
  int tid = threadIdx.x;
  int r0 = blockIdx.x * 64;
  int split = blockIdx.y;
  int wave = tid >> 6, lane = tid & 63;
  int quad = lane >> 4, l15 = lane & 15;
  int wh = wave >> 1, wl = wave & 1;   // GEMM1: (hid32, m32); GEMM2: (m32, n32)

  const _Float16* w1g = w1t + (size_t)split * 512 * 64;
  const float* b1g = b1 + split * 512;

  // x B-frags for GEMM1 (cols m = wl*32+mt*16+l15), loaded once
  half8 xb[2][2];
#pragma unroll
  for (int mt = 0; mt < 2; mt++)
#pragma unroll
    for (int ks = 0; ks < 2; ks++) {
      const float* xr = &x[(size_t)(r0 + wl * 32 + mt * 16 + l15) * 64 +
                           ks * 32 + quad * 8];
      float4 f0 = *(const float4*)xr;
      float4 f1 = *(const float4*)(xr + 4);
      xb[mt][ks] = (half8){(_Float16)f0.x, (_Float16)f0.y, (_Float16)f0.z,
                           (_Float16)f0.w, (_Float16)f1.x, (_Float16)f1.y,
                           (_Float16)f1.z, (_Float16)f1.w};
    }

  f32x4 acc[2][2];   // GEMM2: row m = wh*32+mt*16+quad*4+r, col n = wl*32+nt*16+l15
#pragma unroll
  for (int mt = 0; mt < 2; mt++)
#pragma unroll
    for (int nt = 0; nt < 2; nt++) {
      float bv = (split == 0) ? b2[wl * 32 + nt * 16 + l15] : 0.f;
      acc[mt][nt] = (f32x4){bv, bv, bv, bv};
    }

  int buf = 0;
  for (int c = 0; c < 8; c++) {
    // W1 A-frags: rows hid = c*64 + wh*32 + ht*16 + l15 (coalesced 1 KB/wave)
    half8 a1[2][2];
#pragma unroll
    for (int ht = 0; ht < 2; ht++)
#pragma unroll
      for (int ks = 0; ks < 2; ks++)
        a1[ht][ks] = *(const half8*)&w1g[(size_t)(c * 64 + wh * 32 + ht * 16 + l15) * 64 +
                                         ks * 32 + quad * 8];
    // W2 B-frags for GEMM2: rows n = wl*32+nt*16+l15, k = hid chunk
    half8 b2f[2][2];
#pragma unroll
    for (int nt = 0; nt < 2; nt++)
#pragma unroll
      for (int ks = 0; ks < 2; ks++)
        b2f[nt][ks] = *(const half8*)&w2t[(size_t)(wl * 32 + nt * 16 + l15) * 2048 +
                                          split * 512 + c * 64 + ks * 32 + quad * 8];
    // GEMM1^T: Ht[hid 64][m 64]
    f32x4 hacc[2][2];
#pragma unroll
    for (int ht = 0; ht < 2; ht++)
#pragma unroll
      for (int mt = 0; mt < 2; mt++) hacc[ht][mt] = (f32x4){0.f, 0.f, 0.f, 0.f};
#pragma unroll
    for (int ks = 0; ks < 2; ks++)
#pragma unroll
      for (int ht = 0; ht < 2; ht++)
#pragma unroll
        for (int mt = 0; mt < 2; mt++)
          hacc[ht][mt] = __builtin_amdgcn_mfma_f32_16x16x32_f16(
              a1[ht][ks], xb[mt][ks], hacc[ht][mt], 0, 0, 0);
    // bias + relu + pack: hid = wh*32+ht*16+quad*4+r, m = wl*32+mt*16+l15
#pragma unroll
    for (int ht = 0; ht < 2; ht++) {
      float4 bb = *(const float4*)&b1g[c * 64 + wh * 32 + ht * 16 + quad * 4];
#pragma unroll
      for (int mt = 0; mt < 2; mt++) {
        f32x4 hv = hacc[ht][mt];
        half4v hp = (half4v){
            (_Float16)fmaxf(hv[0] + bb.x, 0.f), (_Float16)fmaxf(hv[1] + bb.y, 0.f),
            (_Float16)fmaxf(hv[2] + bb.z, 0.f), (_Float16)fmaxf(hv[3] + bb.w, 0.f)};
        *(half4v*)&hs[buf][SW64(wl * 32 + mt * 16 + l15,
                                wh * 32 + ht * 16 + quad * 4)] = hp;
      }
    }
    __syncthreads();
    // GEMM2: acc += H[m][h64] @ W2c[h64][n]
#pragma unroll
    for (int ks = 0; ks < 2; ks++)
#pragma unroll
      for (int mt = 0; mt < 2; mt++) {
        half8 a2 = *(const half8*)&hs[buf][SW64(wh * 32 + mt * 16 + l15,
                                                ks * 32 + quad * 8)];
#pragma unroll
        for (int nt = 0; nt < 2; nt++)
          acc[mt][nt] = __builtin_amdgcn_mfma_f32_16x16x32_f16(a2, b2f[nt][ks],
                                                               acc[mt][nt], 0, 0, 0);
      }
    buf ^= 1;
  }
#pragma unroll
  for (int mt = 0; mt < 2; mt++)
#pragma unroll
    for (int nt = 0; nt < 2; nt++)
#pragma unroll
      for (int r = 0; r < 4; r++) {
        int row = r0 + wh * 32 + mt * 16 + quad * 4 + r;
        int col = wl * 32 + nt * 16 + l15;
        out[(size_t)split * ((size_t)BL * 64) + (size_t)row * 64 + col] =
            acc[mt][nt][r];
      }
}

// ---------------- residual(4 parts) + LayerNorm, float4-vectorized ----------------
__global__ __launch_bounds__(256) void k_resln4(
    float* __restrict__ x, const float* __restrict__ tmp,
    const float* __restrict__ sc, const float* __restrict__ bs)
{
  int lane = threadIdx.x & 63;
  int sub = lane & 15;
  int row = blockIdx.x * 16 + (threadIdx.x >> 6) * 4 + (lane >> 4);
  size_t off = (size_t)row * 64 + sub * 4;
  float4 v = *(const float4*)&x[off];
#pragma unroll
  for (int p = 0; p < 4; p++) {
    float4 t = *(const float4*)&tmp[(size_t)p * ((size_t)BL * 64) + off];
    v.x += t.x; v.y += t.y; v.z += t.z; v.w += t.w;
  }
  float sum = v.x + v.y + v.z + v.w;
#pragma unroll
  for (int o = 1; o < 16; o <<= 1) sum += __shfl_xor(sum, o);
  float mean = sum * (1.f / 64.f);
  float4 d = {v.x - mean, v.y - mean, v.z - mean, v.w - mean};
  float sq = d.x * d.x + d.y * d.y + d.z * d.z + d.w * d.w;
#pragma unroll
  for (int o = 1; o < 16; o <<= 1) sq += __shfl_xor(sq, o);
  float rs = rsqrtf(sq * (1.f / 64.f) + 1e-5f);
  float4 s4 = *(const float4*)&sc[sub * 4];
  float4 b4 = *(const float4*)&bs[sub * 4];
  float4 o4 = {d.x * rs * s4.x + b4.x, d.y * rs * s4.y + b4.y,
               d.z * rs * s4.z + b4.z, d.w * rs * s4.w + b4.w};
  *(float4*)&x[off] = o4;
}

// ---------------- head: out[B,V,3] = x[:, -1] @ W_head + b_head ----------------
__global__ __launch_bounds__(256) void k_head(
    const float* __restrict__ x, const float* __restrict__ Wh,
    const float* __restrict__ bh, float* __restrict__ out)
{
  int id = blockIdx.x * 256 + threadIdx.x;  // < B*V = 1024
  int b = id >> 6, v = id & 63;
  const float* xr = x + (size_t)(b * LL + (SS - 1) * VVV + v) * 64;
  float a0 = bh[0], a1 = bh[1], a2 = bh[2];
  for (int e = 0; e < 64; e++) {
    float xv = xr[e];
    a0 += xv * Wh[e * 3 + 0];
    a1 += xv * Wh[e * 3 + 1];
    a2 += xv * Wh[e * 3 + 2];
  }
  out[id * 3 + 0] = a0;
  out[id * 3 + 1] = a1;
  out[id * 3 + 2] = a2;
}

extern "C" void kernel_launch(void* const* d_in, const int* in_sizes, int n_in,
                              void* d_out, int out_size, void* d_ws, size_t ws_size,
                              hipStream_t stream) {
  const float* features = (const float*)d_in[0];
  const int*   ovtag    = (const int*)d_in[1];
  const int*   poiid    = (const int*)d_in[2];
  const float* W_raw    = (const float*)d_in[3];
  const float* b_raw    = (const float*)d_in[4];
  const float* pos_tab  = (const float*)d_in[5];
  const float* type_tab = (const float*)d_in[6];
  const float* poi_tab  = (const float*)d_in[7];
  const float* ov_tab   = (const float*)d_in[8];
  const float* W_comb   = (const float*)d_in[9];
  const float* b_comb   = (const float*)d_in[10];
  const float* Wqkv     = (const float*)d_in[11];
  const float* bqkv     = (const float*)d_in[12];
  const float* Wo       = (const float*)d_in[13];
  const float* bo       = (const float*)d_in[14];
  const float* ln1_s    = (const float*)d_in[15];
  const float* ln1_b    = (const float*)d_in[16];
  const float* W1       = (const float*)d_in[17];
  const float* b1       = (const float*)d_in[18];
  const float* W2       = (const float*)d_in[19];
  const float* b2       = (const float*)d_in[20];
  const float* ln2_s    = (const float*)d_in[21];
  const float* ln2_b    = (const float*)d_in[22];
  const float* W_head   = (const float*)d_in[23];
  const float* b_head   = (const float*)d_in[24];
  float* out = (float*)d_out;
  float* ws  = (float*)d_ws;

  float* zm  = ws;                              // BL
  float* x   = zm + BL;                         // BL*64
  float* tmp = x + (size_t)BL * 64;             // 4 * BL*64
  _Float16* qkv16  = (_Float16*)(tmp + 4 * (size_t)BL * 64);  // BL*192
  _Float16* obuf16 = qkv16 + (size_t)BL * 192;                // BL*64
  _Float16* wcombt = obuf16 + (size_t)BL * 64;                // 64*80
  _Float16* w1t    = wcombt + 5120;                           // NL*2048*64
  _Float16* w2t    = w1t + (size_t)NLAYER * PERL;             // NL*64*2048
  _Float16* wqkvt  = w2t + (size_t)NLAYER * PERL;             // NL*192*64
  _Float16* wot    = wqkvt + (size_t)NLAYER * 192 * 64;       // NL*64*64

  k_prep<<<274, 256, 0, stream>>>(W1, W2, Wqkv, Wo, W_comb,
                                  w1t, w2t, wqkvt, wot, wcombt);
  k_embcomb<<<256, 256, 0, stream>>>(features, ovtag, poiid, W_raw, b_raw,
                                     ov_tab, poi_tab, wcombt, b_comb,
                                     pos_tab, type_tab, x, zm);
  for (int l = 0; l < NLAYER; l++) {
    k_qkv<<<dim3(256, 3), 256, 0, stream>>>(
        x, wqkvt + (size_t)l * 192 * 64, bqkv + l * 192, qkv16);
    k_attn2<<<512, 256, 0, stream>>>(qkv16, zm, obuf16);
    k_oln2<<<256, 256, 0, stream>>>(obuf16, wot + (size_t)l * 4096, bo + l * EE,
                                    x, ln1_s + l * EE, ln1_b + l * EE);
    k_ffn4<<<dim3(256, 4), 256, 0, stream>>>(
        x, w1t + (size_t)l * PERL, w2t + (size_t)l * PERL,
        b1 + l * DFF_, b2 + l * EE, tmp);
    k_resln4<<<BL / 16, 256, 0, stream>>>(x, tmp, ln2_s + l * EE, ln2_b + l * EE);
  }
  k_head<<<4, 256, 0, stream>>>(x, W_head, b_head, out);
}

// Round 7
// 369.740 us; speedup vs baseline: 1.6629x; 1.2427x over previous
//
#include <hip/hip_runtime.h>
#include <math.h>

#define BB 16
#define SS 16
#define VVV 64
#define EE 64
#define HHH 8
#define NLAYER 4
#define DFF_ 2048
#define LL 1024   /* S*V */
#define BL 16384  /* B*L */
#define PERL 131072  /* 64*2048 elems per layer of W1 (and W2); also 32 tiles*4096 */

typedef __attribute__((ext_vector_type(8))) _Float16 half8;
typedef __attribute__((ext_vector_type(4))) _Float16 half4v;
typedef __attribute__((ext_vector_type(2))) _Float16 half2v;
typedef __attribute__((ext_vector_type(4))) float f32x4;

#if defined(__has_builtin)
#if __has_builtin(__builtin_amdgcn_fdot2)
#define HAVE_FDOT2 1
#endif
#endif

// XOR-swizzled index into row-major fp16 LDS tiles with 64-half (128 B) rows.
#define SW64(m, k)  (((m) << 6) + ((((k) >> 3) ^ ((m) & 7)) << 3) + ((k) & 7))

// Fragment-linear tile layout (64x64 fp16 = 4096 halves = 8 frags of 512):
//   element A[m][k]  ->  frag_id = (m>>4)*2 + (k>>5); lane = ((k>>3)&3)*16 + (m&15)
//   half addr = frag_id*512 + lane*8 + (k&7).
// A wave loading frag f reads tile_base + f*512 + lane*8  ->  contiguous 1 KB.

// ---------------- prep: weights -> fp16 fragment-linear tiles (one dispatch) ----------
__global__ __launch_bounds__(256) void k_prep(
    const float* __restrict__ W1, const float* __restrict__ W2,
    const float* __restrict__ Wqkv, const float* __restrict__ Wo,
    const float* __restrict__ Wcomb,
    _Float16* __restrict__ w1f, _Float16* __restrict__ w2f,
    _Float16* __restrict__ wqkvf, _Float16* __restrict__ wof,
    _Float16* __restrict__ wcombt)
{
  __shared__ float t[64 * 65];
  int bx = blockIdx.x;
  int cc = threadIdx.x & 63, rr = threadIdx.x >> 6;

  if (bx >= 272) {  // Wcomb [80][64] -> wcombt [64][80] (plain transpose)
    int r0 = (bx - 272) * 64;
#pragma unroll
    for (int i = 0; i < 16; i++) {
      int r = i * 4 + rr;
      if (r0 + r < 80) t[r * 65 + cc] = Wcomb[(size_t)(r0 + r) * 64 + cc];
    }
    __syncthreads();
#pragma unroll
    for (int i = 0; i < 16; i++) {
      int c = i * 4 + rr;
      if (r0 + c < 80) wcombt[(size_t)cc * 80 + r0 + c] = (_Float16)t[c * 65 + cc];
    }
    return;
  }

  // fragment-linear tiles: S[a][b2] staged transposed (t[b2][a]); A[m][k] = S[k][m]
  const float* src; _Float16* dst; int astr;
  if (bx < 128) {        // W1 [64 k][2048 hid]: tile g = hid block
    int l = bx >> 5, g = bx & 31;
    src = W1 + (size_t)l * PERL + g * 64; astr = 2048;
    dst = w1f + (size_t)(l * 32 + g) * 4096;
  } else if (bx < 256) { // W2 [2048 k][64 n]: tile g = k block
    int j = bx - 128; int l = j >> 5, g = j & 31;
    src = W2 + (size_t)l * PERL + (size_t)g * 64 * 64; astr = 64;
    dst = w2f + (size_t)(l * 32 + g) * 4096;
  } else if (bx < 268) { // Wqkv [64 k][192 n]: 3 tiles per layer
    int j = bx - 256; int l = j / 3, g = j % 3;
    src = Wqkv + (size_t)l * 64 * 192 + g * 64; astr = 192;
    dst = wqkvf + (size_t)(l * 3 + g) * 4096;
  } else {               // Wo [64 k][64 n]
    int l = bx - 268;
    src = Wo + (size_t)l * 4096; astr = 64;
    dst = wof + (size_t)l * 4096;
  }
#pragma unroll
  for (int i = 0; i < 16; i++) {
    int a = i * 4 + rr;
    t[cc * 65 + a] = src[(size_t)a * astr + cc];  // t[m][k] = S[k][m]
  }
  __syncthreads();
#pragma unroll
  for (int it = 0; it < 2; it++) {
    int c = threadIdx.x + it * 256;       // 0..511 half8 slots
    int frag = c >> 6, lane = c & 63;
    int m = (frag >> 1) * 16 + (lane & 15);
    int k0 = (frag & 1) * 32 + (lane >> 4) * 8;
    const float* tr = &t[m * 65 + k0];
    half8 h;
#pragma unroll
    for (int j = 0; j < 8; j++) h[j] = (_Float16)tr[j];
    *(half8*)&dst[(size_t)c * 8] = h;
  }
}

// ------- fused embed + comb GEMM: x = concat@W_comb + b_comb + pos + type; also zm -------
__global__ __launch_bounds__(256) void k_embcomb(
    const float* __restrict__ features, const int* __restrict__ ovtag,
    const int* __restrict__ poiid, const float* __restrict__ W_raw,
    const float* __restrict__ b_raw, const float* __restrict__ ov_tab,
    const float* __restrict__ poi_tab, const _Float16* __restrict__ wcombt,
    const float* __restrict__ b_comb, const float* __restrict__ pos_tab,
    const float* __restrict__ type_tab, float* __restrict__ x,
    float* __restrict__ zm)
{
  constexpr int KP = 104;
  __shared__ _Float16 As[64 * KP];
  __shared__ _Float16 Bs[64 * KP];
  int tid = threadIdx.x;
  int m0 = blockIdx.x * 64;
  int wave = tid >> 6, lane = tid & 63, quad = lane >> 4, l15 = lane & 15;
  int wm = wave >> 1, wn = wave & 1;
  for (int p = tid; p < 1536; p += 256) {
    int r = p / 24, s = p - r * 24; int c = s * 4;
    int row = m0 + r;
    float f0 = features[row * 3 + 0];
    float f1 = features[row * 3 + 1];
    float f2 = features[row * 3 + 2];
    if (s == 0) zm[row] = ((f0 + f1 + f2) == 0.f) ? 1.f : 0.f;
    half4v h;
#pragma unroll
    for (int j = 0; j < 4; j++) {
      int cc = c + j; float v;
      if (cc < 64) {
        v = b_raw[cc] + f0 * W_raw[cc] + f1 * W_raw[64 + cc] + f2 * W_raw[128 + cc];
      } else if (cc < 72) {
        int tt = ovtag[row]; v = (tt <= 0) ? 0.f : ov_tab[tt * 8 + cc - 64];
      } else if (cc < 80) {
        int tt = poiid[row]; v = (tt <= 0) ? 0.f : poi_tab[tt * 8 + cc - 72];
      } else v = 0.f;
      h[j] = (_Float16)v;
    }
    *(half4v*)&As[r * KP + c] = h;
  }
  for (int p = tid; p < 1536; p += 256) {
    int r = p / 24, s = p - r * 24; int c = s * 4;
    half4v h = (half4v){0, 0, 0, 0};
    if (c < 80) h = *(const half4v*)&wcombt[r * 80 + c];
    *(half4v*)&Bs[r * KP + c] = h;
  }
  __syncthreads();
  f32x4 acc[2][2];
#pragma unroll
  for (int mt = 0; mt < 2; mt++)
#pragma unroll
    for (int nt = 0; nt < 2; nt++) {
      float bv = b_comb[wn * 32 + nt * 16 + l15];
      acc[mt][nt] = (f32x4){bv, bv, bv, bv};
    }
#pragma unroll
  for (int ks = 0; ks < 3; ks++) {
    half8 af[2], bf[2];
#pragma unroll
    for (int mt = 0; mt < 2; mt++)
      af[mt] = *(const half8*)&As[(wm * 32 + mt * 16 + l15) * KP + ks * 32 + quad * 8];
#pragma unroll
    for (int nt = 0; nt < 2; nt++)
      bf[nt] = *(const half8*)&Bs[(wn * 32 + nt * 16 + l15) * KP + ks * 32 + quad * 8];
#pragma unroll
    for (int mt = 0; mt < 2; mt++)
#pragma unroll
      for (int nt = 0; nt < 2; nt++)
        acc[mt][nt] = __builtin_amdgcn_mfma_f32_16x16x32_f16(af[mt], bf[nt],
                                                             acc[mt][nt], 0, 0, 0);
  }
#pragma unroll
  for (int mt = 0; mt < 2; mt++)
#pragma unroll
    for (int nt = 0; nt < 2; nt++)
#pragma unroll
      for (int r = 0; r < 4; r++) {
        int row = m0 + wm * 32 + mt * 16 + quad * 4 + r;
        int col = wn * 32 + nt * 16 + l15;
        int l = row & (LL - 1);
        x[(size_t)row * 64 + col] = acc[mt][nt][r] +
            pos_tab[(l >> 6) * 64 + col] + type_tab[(l & 63) * 64 + col];
      }
}

// ---- QKV GEMM: weight frags coalesced (fragment-linear); K/V out in [b][h][row][8] ----
__global__ __launch_bounds__(256) void k_qkv(
    const float* __restrict__ x, const _Float16* __restrict__ wqkvf,
    const float* __restrict__ bias, _Float16* __restrict__ qbuf,
    _Float16* __restrict__ kbuf, _Float16* __restrict__ vbuf)
{
  int tid = threadIdx.x;
  int m0 = blockIdx.x * 64, n0 = blockIdx.y * 64;
  int wave = tid >> 6, lane = tid & 63, quad = lane >> 4, l15 = lane & 15;
  int wm = wave >> 1, wn = wave & 1;
  const _Float16* bt = wqkvf + (size_t)blockIdx.y * 4096;
  half8 af[2][2], bf[2][2];
#pragma unroll
  for (int mt = 0; mt < 2; mt++)
#pragma unroll
    for (int ks = 0; ks < 2; ks++) {
      const float* xr = &x[(size_t)(m0 + wm * 32 + mt * 16 + l15) * 64 +
                           ks * 32 + quad * 8];
      float4 f0 = *(const float4*)xr;
      float4 f1 = *(const float4*)(xr + 4);
      af[mt][ks] = (half8){(_Float16)f0.x, (_Float16)f0.y, (_Float16)f0.z,
                           (_Float16)f0.w, (_Float16)f1.x, (_Float16)f1.y,
                           (_Float16)f1.z, (_Float16)f1.w};
    }
#pragma unroll
  for (int nt = 0; nt < 2; nt++)
#pragma unroll
    for (int ks = 0; ks < 2; ks++)
      bf[nt][ks] = *(const half8*)&bt[(size_t)(((wn * 2 + nt) * 2 + ks) * 512) +
                                      lane * 8];
  f32x4 acc[2][2];
#pragma unroll
  for (int mt = 0; mt < 2; mt++)
#pragma unroll
    for (int nt = 0; nt < 2; nt++) {
      float bv = bias[n0 + wn * 32 + nt * 16 + l15];
      acc[mt][nt] = (f32x4){bv, bv, bv, bv};
    }
#pragma unroll
  for (int ks = 0; ks < 2; ks++)
#pragma unroll
    for (int mt = 0; mt < 2; mt++)
#pragma unroll
      for (int nt = 0; nt < 2; nt++)
        acc[mt][nt] = __builtin_amdgcn_mfma_f32_16x16x32_f16(af[mt][ks], bf[nt][ks],
                                                             acc[mt][nt], 0, 0, 0);
#pragma unroll
  for (int mt = 0; mt < 2; mt++)
#pragma unroll
    for (int nt = 0; nt < 2; nt++) {
      int col = wn * 32 + nt * 16 + l15;
#pragma unroll
      for (int r = 0; r < 4; r++) {
        int row = m0 + wm * 32 + mt * 16 + quad * 4 + r;
        _Float16 v = (_Float16)acc[mt][nt][r];
        if (blockIdx.y == 0) {
          qbuf[(size_t)row * 64 + col] = v;
        } else {
          _Float16* dst = (blockIdx.y == 1) ? kbuf : vbuf;
          int h = col >> 3, d = col & 7;
          int b = row >> 10, rb = row & 1023;
          dst[((size_t)(b * 8 + h) * 1024 + rb) * 8 + d] = v;
        }
      }
    }
}

// ------- attention: coalesced K/V staging; output in A-fragment-linear layout -------
__global__ __launch_bounds__(256) void k_attn2(
    const _Float16* __restrict__ qbuf, const _Float16* __restrict__ kbuf,
    const _Float16* __restrict__ vbuf, const float* __restrict__ zm,
    _Float16* __restrict__ obuf)
{
  __shared__ _Float16 Ks[1024 * 8];   // 16 KB
  __shared__ _Float16 Vs[1024 * 8];   // 16 KB
  __shared__ float zs[1024];          // 4 KB
  int blk = blockIdx.x;
  int qb = blk & 3, h = (blk >> 2) & 7, b = blk >> 5;
  const _Float16* kb = kbuf + (size_t)(b * 8 + h) * 8192;
  const _Float16* vb = vbuf + (size_t)(b * 8 + h) * 8192;
  for (int p = threadIdx.x; p < 1024; p += 256) {
    *(half8*)&Ks[p * 8] = *(const half8*)&kb[p * 8];
    *(half8*)&Vs[p * 8] = *(const half8*)&vb[p * 8];
    zs[p] = zm[b * LL + p];
  }
  __syncthreads();
  int qrow = qb * 256 + threadIdx.x;
  int tq = qrow >> 6, vq = qrow & 63;
  half8 qh = *(const half8*)&qbuf[(size_t)(b * LL + qrow) * 64 + h * 8];
  const float scale = 0.3535533905932738f;
  float m = -INFINITY, lsum = 0.f;
  float acc[8] = {0.f, 0.f, 0.f, 0.f, 0.f, 0.f, 0.f, 0.f};
  bool zmq = (zs[qrow] != 0.f);

  auto attend = [&](int k) {
    if (zs[k] != 0.f) return;
    half8 kk = *(const half8*)&Ks[k * 8];
    float s = 0.f;
#ifdef HAVE_FDOT2
#pragma unroll
    for (int j = 0; j < 4; j++) {
      half2v qa = (half2v){qh[2 * j], qh[2 * j + 1]};
      half2v ka = (half2v){kk[2 * j], kk[2 * j + 1]};
      s = __builtin_amdgcn_fdot2(qa, ka, s, false);
    }
#else
#pragma unroll
    for (int j = 0; j < 8; j++) s += (float)qh[j] * (float)kk[j];
#endif
    s *= scale;
    half8 vv = *(const half8*)&Vs[k * 8];
    if (s <= m) {
      float p = __expf(s - m);
      lsum += p;
#pragma unroll
      for (int d = 0; d < 8; d++) acc[d] += p * (float)vv[d];
    } else {
      float r = __expf(m - s);
      lsum = lsum * r + 1.f;
#pragma unroll
      for (int d = 0; d < 8; d++) acc[d] = acc[d] * r + (float)vv[d];
      m = s;
    }
  };

  if (!zmq) {
    for (int vv = 0; vv < 64; vv++) attend(tq * 64 + vv);   // wave-uniform k
    for (int tt = 0; tt < 16; tt++) {
      if (tt == tq) continue;
      attend(tt * 64 + vq);
    }
  }
  float inv = 1.f / lsum;
  half8 o;
#pragma unroll
  for (int d = 0; d < 8; d++) o[d] = (_Float16)(acc[d] * inv);
  // A-fragment-linear store: tile = global row / 64; m = qrow&63, k = h*8+d
  size_t tile = (size_t)(b * 16 + (qrow >> 6));
  int frag = ((qrow >> 4) & 3) * 2 + (h >> 2);
  int flane = (h & 3) * 16 + (qrow & 15);
  *(half8*)&obuf[tile * 4096 + frag * 512 + flane * 8] = o;
}

// ---- fused o-proj + residual + LN1: A/B frags fragment-linear (coalesced); 1 barrier ----
__global__ __launch_bounds__(256) void k_oln2(
    const _Float16* __restrict__ obuf, const _Float16* __restrict__ wof,
    const float* __restrict__ bo, float* __restrict__ x,
    const float* __restrict__ ln_s, const float* __restrict__ ln_b)
{
  __shared__ float ots[64 * 68];
  int tid = threadIdx.x;
  int m0 = blockIdx.x * 64;
  int wave = tid >> 6, lane = tid & 63, quad = lane >> 4, l15 = lane & 15;
  int wm = wave >> 1, wn = wave & 1;
  const _Float16* ot = obuf + (size_t)blockIdx.x * 4096;
  half8 af[2][2], bf[2][2];
#pragma unroll
  for (int mt = 0; mt < 2; mt++)
#pragma unroll
    for (int ks = 0; ks < 2; ks++)
      af[mt][ks] = *(const half8*)&ot[(size_t)(((wm * 2 + mt) * 2 + ks) * 512) +
                                      lane * 8];
#pragma unroll
  for (int nt = 0; nt < 2; nt++)
#pragma unroll
    for (int ks = 0; ks < 2; ks++)
      bf[nt][ks] = *(const half8*)&wof[(size_t)(((wn * 2 + nt) * 2 + ks) * 512) +
                                       lane * 8];
  f32x4 acc[2][2];
#pragma unroll
  for (int mt = 0; mt < 2; mt++)
#pragma unroll
    for (int nt = 0; nt < 2; nt++) {
      float bv = bo[wn * 32 + nt * 16 + l15];
      acc[mt][nt] = (f32x4){bv, bv, bv, bv};
    }
#pragma unroll
  for (int ks = 0; ks < 2; ks++)
#pragma unroll
    for (int mt = 0; mt < 2; mt++)
#pragma unroll
      for (int nt = 0; nt < 2; nt++)
        acc[mt][nt] = __builtin_amdgcn_mfma_f32_16x16x32_f16(af[mt][ks], bf[nt][ks],
                                                             acc[mt][nt], 0, 0, 0);
#pragma unroll
  for (int mt = 0; mt < 2; mt++)
#pragma unroll
    for (int nt = 0; nt < 2; nt++)
#pragma unroll
      for (int r = 0; r < 4; r++)
        ots[(wm * 32 + mt * 16 + quad * 4 + r) * 68 + wn * 32 + nt * 16 + l15] =
            acc[mt][nt][r];
  __syncthreads();
  for (int i = 0; i < 16; i++) {
    int row = wave * 16 + i;
    size_t off = (size_t)(m0 + row) * 64 + lane;
    float val = ots[row * 68 + lane] + x[off];
    float sum = val;
#pragma unroll
    for (int o = 32; o > 0; o >>= 1) sum += __shfl_xor(sum, o);
    float mean = sum * (1.f / 64.f);
    float d = val - mean;
    float sq = d * d;
#pragma unroll
    for (int o = 32; o > 0; o >>= 1) sq += __shfl_xor(sq, o);
    x[off] = d * rsqrtf(sq * (1.f / 64.f) + 1e-5f) * ln_s[lane] + ln_b[lane];
  }
}

// ---- FFN: fragment-linear weights (coalesced frags); dbuf H tile; 1 barrier/chunk ----
// grid (256, 4): split s covers hidden [s*512, s*512+512), 8 chunks of 64.
__global__ __launch_bounds__(256) void k_ffn5(
    const float* __restrict__ x, const _Float16* __restrict__ w1f,
    const _Float16* __restrict__ w2f, const float* __restrict__ b1,
    const float* __restrict__ b2, float* __restrict__ out)
{
  __shared__ _Float16 hs[2][4096];   // dbuf 64m x 64h SW64 — 16 KB total
  int tid = threadIdx.x;
  int r0 = blockIdx.x * 64;
  int split = blockIdx.y;
  int wave = tid >> 6, lane = tid & 63;
  int quad = lane >> 4, l15 = lane & 15;
  int wh = wave >> 1, wl = wave & 1;

  const float* b1g = b1 + split * 512;

  // x B-frags for GEMM1 (cols m = wl*32+mt*16+l15), loaded once
  half8 xb[2][2];
#pragma unroll
  for (int mt = 0; mt < 2; mt++)
#pragma unroll
    for (int ks = 0; ks < 2; ks++) {
      const float* xr = &x[(size_t)(r0 + wl * 32 + mt * 16 + l15) * 64 +
                           ks * 32 + quad * 8];
      float4 f0 = *(const float4*)xr;
      float4 f1 = *(const float4*)(xr + 4);
      xb[mt][ks] = (half8){(_Float16)f0.x, (_Float16)f0.y, (_Float16)f0.z,
                           (_Float16)f0.w, (_Float16)f1.x, (_Float16)f1.y,
                           (_Float16)f1.z, (_Float16)f1.w};
    }

  f32x4 acc[2][2];   // GEMM2: row m = wh*32+mt*16+quad*4+r, col n = wl*32+nt*16+l15
#pragma unroll
  for (int mt = 0; mt < 2; mt++)
#pragma unroll
    for (int nt = 0; nt < 2; nt++) {
      float bv = (split == 0) ? b2[wl * 32 + nt * 16 + l15] : 0.f;
      acc[mt][nt] = (f32x4){bv, bv, bv, bv};
    }

  int buf = 0;
  for (int c = 0; c < 8; c++) {
    int g = split * 8 + c;             // global 64-wide hidden chunk
    const _Float16* w1t_ = w1f + (size_t)g * 4096;
    const _Float16* w2t_ = w2f + (size_t)g * 4096;
    // coalesced fragment loads (1 KB contiguous per wave per load)
    half8 a1[2][2], b2f[2][2];
#pragma unroll
    for (int ht = 0; ht < 2; ht++)
#pragma unroll
      for (int ks = 0; ks < 2; ks++)
        a1[ht][ks] = *(const half8*)&w1t_[(size_t)(((wh * 2 + ht) * 2 + ks) * 512) +
                                          lane * 8];
#pragma unroll
    for (int nt = 0; nt < 2; nt++)
#pragma unroll
      for (int ks = 0; ks < 2; ks++)
        b2f[nt][ks] = *(const half8*)&w2t_[(size_t)(((wl * 2 + nt) * 2 + ks) * 512) +
                                           lane * 8];
    // GEMM1^T: Ht[hid 64][m 64]
    f32x4 hacc[2][2];
#pragma unroll
    for (int ht = 0; ht < 2; ht++)
#pragma unroll
      for (int mt = 0; mt < 2; mt++) hacc[ht][mt] = (f32x4){0.f, 0.f, 0.f, 0.f};
#pragma unroll
    for (int ks = 0; ks < 2; ks++)
#pragma unroll
      for (int ht = 0; ht < 2; ht++)
#pragma unroll
        for (int mt = 0; mt < 2; mt++)
          hacc[ht][mt] = __builtin_amdgcn_mfma_f32_16x16x32_f16(
              a1[ht][ks], xb[mt][ks], hacc[ht][mt], 0, 0, 0);
    // bias + relu + pack: hid = wh*32+ht*16+quad*4+r, m = wl*32+mt*16+l15
#pragma unroll
    for (int ht = 0; ht < 2; ht++) {
      float4 bb = *(const float4*)&b1g[c * 64 + wh * 32 + ht * 16 + quad * 4];
#pragma unroll
      for (int mt = 0; mt < 2; mt++) {
        f32x4 hv = hacc[ht][mt];
        half4v hp = (half4v){
            (_Float16)fmaxf(hv[0] + bb.x, 0.f), (_Float16)fmaxf(hv[1] + bb.y, 0.f),
            (_Float16)fmaxf(hv[2] + bb.z, 0.f), (_Float16)fmaxf(hv[3] + bb.w, 0.f)};
        *(half4v*)&hs[buf][SW64(wl * 32 + mt * 16 + l15,
                                wh * 32 + ht * 16 + quad * 4)] = hp;
      }
    }
    __syncthreads();
    // GEMM2: acc += H[m][h64] @ W2c[h64][n]
#pragma unroll
    for (int ks = 0; ks < 2; ks++)
#pragma unroll
      for (int mt = 0; mt < 2; mt++) {
        half8 a2 = *(const half8*)&hs[buf][SW64(wh * 32 + mt * 16 + l15,
                                                ks * 32 + quad * 8)];
#pragma unroll
        for (int nt = 0; nt < 2; nt++)
          acc[mt][nt] = __builtin_amdgcn_mfma_f32_16x16x32_f16(a2, b2f[nt][ks],
                                                               acc[mt][nt], 0, 0, 0);
      }
    buf ^= 1;
  }
#pragma unroll
  for (int mt = 0; mt < 2; mt++)
#pragma unroll
    for (int nt = 0; nt < 2; nt++)
#pragma unroll
      for (int r = 0; r < 4; r++) {
        int row = r0 + wh * 32 + mt * 16 + quad * 4 + r;
        int col = wl * 32 + nt * 16 + l15;
        out[(size_t)split * ((size_t)BL * 64) + (size_t)row * 64 + col] =
            acc[mt][nt][r];
      }
}

// ---------------- residual(4 parts) + LayerNorm, float4-vectorized ----------------
__global__ __launch_bounds__(256) void k_resln4(
    float* __restrict__ x, const float* __restrict__ tmp,
    const float* __restrict__ sc, const float* __restrict__ bs)
{
  int lane = threadIdx.x & 63;
  int sub = lane & 15;
  int row = blockIdx.x * 16 + (threadIdx.x >> 6) * 4 + (lane >> 4);
  size_t off = (size_t)row * 64 + sub * 4;
  float4 v = *(const float4*)&x[off];
#pragma unroll
  for (int p = 0; p < 4; p++) {
    float4 t = *(const float4*)&tmp[(size_t)p * ((size_t)BL * 64) + off];
    v.x += t.x; v.y += t.y; v.z += t.z; v.w += t.w;
  }
  float sum = v.x + v.y + v.z + v.w;
#pragma unroll
  for (int o = 1; o < 16; o <<= 1) sum += __shfl_xor(sum, o);
  float mean = sum * (1.f / 64.f);
  float4 d = {v.x - mean, v.y - mean, v.z - mean, v.w - mean};
  float sq = d.x * d.x + d.y * d.y + d.z * d.z + d.w * d.w;
#pragma unroll
  for (int o = 1; o < 16; o <<= 1) sq += __shfl_xor(sq, o);
  float rs = rsqrtf(sq * (1.f / 64.f) + 1e-5f);
  float4 s4 = *(const float4*)&sc[sub * 4];
  float4 b4 = *(const float4*)&bs[sub * 4];
  float4 o4 = {d.x * rs * s4.x + b4.x, d.y * rs * s4.y + b4.y,
               d.z * rs * s4.z + b4.z, d.w * rs * s4.w + b4.w};
  *(float4*)&x[off] = o4;
}

// ---------------- head: out[B,V,3] = x[:, -1] @ W_head + b_head ----------------
__global__ __launch_bounds__(256) void k_head(
    const float* __restrict__ x, const float* __restrict__ Wh,
    const float* __restrict__ bh, float* __restrict__ out)
{
  int id = blockIdx.x * 256 + threadIdx.x;  // < B*V = 1024
  int b = id >> 6, v = id & 63;
  const float* xr = x + (size_t)(b * LL + (SS - 1) * VVV + v) * 64;
  float a0 = bh[0], a1 = bh[1], a2 = bh[2];
  for (int e = 0; e < 64; e++) {
    float xv = xr[e];
    a0 += xv * Wh[e * 3 + 0];
    a1 += xv * Wh[e * 3 + 1];
    a2 += xv * Wh[e * 3 + 2];
  }
  out[id * 3 + 0] = a0;
  out[id * 3 + 1] = a1;
  out[id * 3 + 2] = a2;
}

extern "C" void kernel_launch(void* const* d_in, const int* in_sizes, int n_in,
                              void* d_out, int out_size, void* d_ws, size_t ws_size,
                              hipStream_t stream) {
  const float* features = (const float*)d_in[0];
  const int*   ovtag    = (const int*)d_in[1];
  const int*   poiid    = (const int*)d_in[2];
  const float* W_raw    = (const float*)d_in[3];
  const float* b_raw    = (const float*)d_in[4];
  const float* pos_tab  = (const float*)d_in[5];
  const float* type_tab = (const float*)d_in[6];
  const float* poi_tab  = (const float*)d_in[7];
  const float* ov_tab   = (const float*)d_in[8];
  const float* W_comb   = (const float*)d_in[9];
  const float* b_comb   = (const float*)d_in[10];
  const float* Wqkv     = (const float*)d_in[11];
  const float* bqkv     = (const float*)d_in[12];
  const float* Wo       = (const float*)d_in[13];
  const float* bo       = (const float*)d_in[14];
  const float* ln1_s    = (const float*)d_in[15];
  const float* ln1_b    = (const float*)d_in[16];
  const float* W1       = (const float*)d_in[17];
  const float* b1       = (const float*)d_in[18];
  const float* W2       = (const float*)d_in[19];
  const float* b2       = (const float*)d_in[20];
  const float* ln2_s    = (const float*)d_in[21];
  const float* ln2_b    = (const float*)d_in[22];
  const float* W_head   = (const float*)d_in[23];
  const float* b_head   = (const float*)d_in[24];
  float* out = (float*)d_out;
  float* ws  = (float*)d_ws;

  float* zm  = ws;                              // BL
  float* x   = zm + BL;                         // BL*64
  float* tmp = x + (size_t)BL * 64;             // 4 * BL*64
  _Float16* qbuf   = (_Float16*)(tmp + 4 * (size_t)BL * 64);  // BL*64
  _Float16* kbuf   = qbuf + (size_t)BL * 64;                  // BL*64
  _Float16* vbuf   = kbuf + (size_t)BL * 64;                  // BL*64
  _Float16* obuf16 = vbuf + (size_t)BL * 64;                  // BL*64 (frag-linear)
  _Float16* wcombt = obuf16 + (size_t)BL * 64;                // 64*80
  _Float16* w1f    = wcombt + 5120;                           // NL*32*4096 = NL*PERL
  _Float16* w2f    = w1f + (size_t)NLAYER * PERL;             // NL*PERL
  _Float16* wqkvf  = w2f + (size_t)NLAYER * PERL;             // NL*3*4096
  _Float16* wof    = wqkvf + (size_t)NLAYER * 3 * 4096;       // NL*4096

  k_prep<<<274, 256, 0, stream>>>(W1, W2, Wqkv, Wo, W_comb,
                                  w1f, w2f, wqkvf, wof, wcombt);
  k_embcomb<<<256, 256, 0, stream>>>(features, ovtag, poiid, W_raw, b_raw,
                                     ov_tab, poi_tab, wcombt, b_comb,
                                     pos_tab, type_tab, x, zm);
  for (int l = 0; l < NLAYER; l++) {
    k_qkv<<<dim3(256, 3), 256, 0, stream>>>(
        x, wqkvf + (size_t)l * 3 * 4096, bqkv + l * 192, qbuf, kbuf, vbuf);
    k_attn2<<<512, 256, 0, stream>>>(qbuf, kbuf, vbuf, zm, obuf16);
    k_oln2<<<256, 256, 0, stream>>>(obuf16, wof + (size_t)l * 4096, bo + l * EE,
                                    x, ln1_s + l * EE, ln1_b + l * EE);
    k_ffn5<<<dim3(256, 4), 256, 0, stream>>>(
        x, w1f + (size_t)l * PERL, w2f + (size_t)l * PERL,
        b1 + l * DFF_, b2 + l * EE, tmp);
    k_resln4<<<BL / 16, 256, 0, stream>>>(x, tmp, ln2_s + l * EE, ln2_b + l * EE);
  }
  k_head<<<4, 256, 0, stream>>>(x, W_head, b_head, out);
}

// Round 8
// 360.173 us; speedup vs baseline: 1.7071x; 1.0266x over previous
//
#include <hip/hip_runtime.h>
#include <math.h>

#define BB 16
#define SS 16
#define VVV 64
#define EE 64
#define HHH 8
#define NLAYER 4
#define DFF_ 2048
#define LL 1024   /* S*V */
#define BL 16384  /* B*L */
#define PERL 131072  /* 64*2048 elems per layer of W1 (and W2); 32 tiles*4096 */

typedef __attribute__((ext_vector_type(8))) _Float16 half8;
typedef __attribute__((ext_vector_type(4))) _Float16 half4v;
typedef __attribute__((ext_vector_type(2))) _Float16 half2v;
typedef __attribute__((ext_vector_type(4))) float f32x4;

#if defined(__has_builtin)
#if __has_builtin(__builtin_amdgcn_fdot2)
#define HAVE_FDOT2 1
#endif
#endif

// XOR-swizzled index into row-major fp16 LDS tiles with 64-half (128 B) rows.
#define SW64(m, k)  (((m) << 6) + ((((k) >> 3) ^ ((m) & 7)) << 3) + ((k) & 7))

// Fragment-linear tile layout (64x64 fp16 = 8 frags of 512 halves):
//   A[m][k] -> frag = (m>>4)*2 + (k>>5); lane = ((k>>3)&3)*16 + (m&15); +(k&7)
// Wave loading frag f reads tile_base + f*512 + lane*8 -> contiguous 1 KB.

// ---------------- prep: weights -> fp16 fragment-linear tiles (one dispatch) ----------
__global__ __launch_bounds__(256) void k_prep(
    const float* __restrict__ W1, const float* __restrict__ W2,
    const float* __restrict__ Wqkv, const float* __restrict__ Wo,
    const float* __restrict__ Wcomb,
    _Float16* __restrict__ w1f, _Float16* __restrict__ w2f,
    _Float16* __restrict__ wqkvf, _Float16* __restrict__ wof,
    _Float16* __restrict__ wcombt)
{
  __shared__ float t[64 * 65];
  int bx = blockIdx.x;
  int cc = threadIdx.x & 63, rr = threadIdx.x >> 6;

  if (bx >= 272) {  // Wcomb [80][64] -> wcombt [64][80] (plain transpose)
    int r0 = (bx - 272) * 64;
#pragma unroll
    for (int i = 0; i < 16; i++) {
      int r = i * 4 + rr;
      if (r0 + r < 80) t[r * 65 + cc] = Wcomb[(size_t)(r0 + r) * 64 + cc];
    }
    __syncthreads();
#pragma unroll
    for (int i = 0; i < 16; i++) {
      int c = i * 4 + rr;
      if (r0 + c < 80) wcombt[(size_t)cc * 80 + r0 + c] = (_Float16)t[c * 65 + cc];
    }
    return;
  }

  const float* src; _Float16* dst; int astr;
  if (bx < 128) {        // W1 [64 k][2048 hid]: tile g = hid block
    int l = bx >> 5, g = bx & 31;
    src = W1 + (size_t)l * PERL + g * 64; astr = 2048;
    dst = w1f + (size_t)(l * 32 + g) * 4096;
  } else if (bx < 256) { // W2 [2048 k][64 n]: tile g = k block
    int j = bx - 128; int l = j >> 5, g = j & 31;
    src = W2 + (size_t)l * PERL + (size_t)g * 64 * 64; astr = 64;
    dst = w2f + (size_t)(l * 32 + g) * 4096;
  } else if (bx < 268) { // Wqkv [64 k][192 n]: 3 tiles per layer
    int j = bx - 256; int l = j / 3, g = j % 3;
    src = Wqkv + (size_t)l * 64 * 192 + g * 64; astr = 192;
    dst = wqkvf + (size_t)(l * 3 + g) * 4096;
  } else {               // Wo [64 k][64 n]
    int l = bx - 268;
    src = Wo + (size_t)l * 4096; astr = 64;
    dst = wof + (size_t)l * 4096;
  }
#pragma unroll
  for (int i = 0; i < 16; i++) {
    int a = i * 4 + rr;
    t[cc * 65 + a] = src[(size_t)a * astr + cc];  // t[m][k] = S[k][m]
  }
  __syncthreads();
#pragma unroll
  for (int it = 0; it < 2; it++) {
    int c = threadIdx.x + it * 256;       // 0..511 half8 slots
    int frag = c >> 6, lane = c & 63;
    int m = (frag >> 1) * 16 + (lane & 15);
    int k0 = (frag & 1) * 32 + (lane >> 4) * 8;
    const float* tr = &t[m * 65 + k0];
    half8 h;
#pragma unroll
    for (int j = 0; j < 8; j++) h[j] = (_Float16)tr[j];
    *(half8*)&dst[(size_t)c * 8] = h;
  }
}

// ---- shared QKV phase: x fp16 in LDS (SW64) -> Q/K/V gemm + scatter stores ----
__device__ __forceinline__ void qkv_phase(
    const _Float16* xs, const _Float16* __restrict__ wqkvf,
    const float* __restrict__ bqkv, _Float16* __restrict__ qbuf,
    _Float16* __restrict__ kbuf, _Float16* __restrict__ vbuf,
    int bx, int wave, int lane)
{
  int quad = lane >> 4, l15 = lane & 15;
  int wm = wave >> 1, wn = wave & 1;
  half8 af[2][2];
#pragma unroll
  for (int mt = 0; mt < 2; mt++)
#pragma unroll
    for (int ks = 0; ks < 2; ks++)
      af[mt][ks] = *(const half8*)&xs[SW64(wm * 32 + mt * 16 + l15,
                                           ks * 32 + quad * 8)];
  for (int nb = 0; nb < 3; nb++) {
    const _Float16* bt = wqkvf + (size_t)nb * 4096;
    half8 bf[2][2];
#pragma unroll
    for (int nt = 0; nt < 2; nt++)
#pragma unroll
      for (int ks = 0; ks < 2; ks++)
        bf[nt][ks] = *(const half8*)&bt[(size_t)(((wn * 2 + nt) * 2 + ks) * 512) +
                                        lane * 8];
    f32x4 acc[2][2];
#pragma unroll
    for (int mt = 0; mt < 2; mt++)
#pragma unroll
      for (int nt = 0; nt < 2; nt++) {
        float bv = bqkv[nb * 64 + wn * 32 + nt * 16 + l15];
        acc[mt][nt] = (f32x4){bv, bv, bv, bv};
      }
#pragma unroll
    for (int ks = 0; ks < 2; ks++)
#pragma unroll
      for (int mt = 0; mt < 2; mt++)
#pragma unroll
        for (int nt = 0; nt < 2; nt++)
          acc[mt][nt] = __builtin_amdgcn_mfma_f32_16x16x32_f16(
              af[mt][ks], bf[nt][ks], acc[mt][nt], 0, 0, 0);
#pragma unroll
    for (int mt = 0; mt < 2; mt++)
#pragma unroll
      for (int nt = 0; nt < 2; nt++) {
        int col = wn * 32 + nt * 16 + l15;
#pragma unroll
        for (int r = 0; r < 4; r++) {
          int row = bx * 64 + wm * 32 + mt * 16 + quad * 4 + r;
          _Float16 v = (_Float16)acc[mt][nt][r];
          if (nb == 0) {
            qbuf[(size_t)row * 64 + col] = v;
          } else {
            _Float16* dst = (nb == 1) ? kbuf : vbuf;
            int h = col >> 3, d = col & 7;
            int b = row >> 10, rb = row & 1023;
            dst[((size_t)(b * 8 + h) * 1024 + rb) * 8 + d] = v;
          }
        }
      }
  }
}

// ------- fused embed + comb GEMM + pos/type + QKV(layer0): writes x1, zm, q/k/v -------
__global__ __launch_bounds__(256) void k_embqkv(
    const float* __restrict__ features, const int* __restrict__ ovtag,
    const int* __restrict__ poiid, const float* __restrict__ W_raw,
    const float* __restrict__ b_raw, const float* __restrict__ ov_tab,
    const float* __restrict__ poi_tab, const _Float16* __restrict__ wcombt,
    const float* __restrict__ b_comb, const float* __restrict__ pos_tab,
    const float* __restrict__ type_tab, float* __restrict__ x1,
    float* __restrict__ zm, const _Float16* __restrict__ wqkvf,
    const float* __restrict__ bqkv, _Float16* __restrict__ qbuf,
    _Float16* __restrict__ kbuf, _Float16* __restrict__ vbuf)
{
  constexpr int KP = 104;
  __shared__ _Float16 As[64 * KP];
  __shared__ _Float16 Bs[64 * KP];
  __shared__ _Float16 xs[4096];
  int tid = threadIdx.x;
  int bx = blockIdx.x;
  int m0 = bx * 64;
  int wave = tid >> 6, lane = tid & 63, quad = lane >> 4, l15 = lane & 15;
  int wm = wave >> 1, wn = wave & 1;
  for (int p = tid; p < 1536; p += 256) {
    int r = p / 24, s = p - r * 24; int c = s * 4;
    int row = m0 + r;
    float f0 = features[row * 3 + 0];
    float f1 = features[row * 3 + 1];
    float f2 = features[row * 3 + 2];
    if (s == 0) zm[row] = ((f0 + f1 + f2) == 0.f) ? 1.f : 0.f;
    half4v h;
#pragma unroll
    for (int j = 0; j < 4; j++) {
      int cc = c + j; float v;
      if (cc < 64) {
        v = b_raw[cc] + f0 * W_raw[cc] + f1 * W_raw[64 + cc] + f2 * W_raw[128 + cc];
      } else if (cc < 72) {
        int tt = ovtag[row]; v = (tt <= 0) ? 0.f : ov_tab[tt * 8 + cc - 64];
      } else if (cc < 80) {
        int tt = poiid[row]; v = (tt <= 0) ? 0.f : poi_tab[tt * 8 + cc - 72];
      } else v = 0.f;
      h[j] = (_Float16)v;
    }
    *(half4v*)&As[r * KP + c] = h;
  }
  for (int p = tid; p < 1536; p += 256) {
    int r = p / 24, s = p - r * 24; int c = s * 4;
    half4v h = (half4v){0, 0, 0, 0};
    if (c < 80) h = *(const half4v*)&wcombt[r * 80 + c];
    *(half4v*)&Bs[r * KP + c] = h;
  }
  __syncthreads();
  f32x4 acc[2][2];
#pragma unroll
  for (int mt = 0; mt < 2; mt++)
#pragma unroll
    for (int nt = 0; nt < 2; nt++) {
      float bv = b_comb[wn * 32 + nt * 16 + l15];
      acc[mt][nt] = (f32x4){bv, bv, bv, bv};
    }
#pragma unroll
  for (int ks = 0; ks < 3; ks++) {
    half8 af[2], bf[2];
#pragma unroll
    for (int mt = 0; mt < 2; mt++)
      af[mt] = *(const half8*)&As[(wm * 32 + mt * 16 + l15) * KP + ks * 32 + quad * 8];
#pragma unroll
    for (int nt = 0; nt < 2; nt++)
      bf[nt] = *(const half8*)&Bs[(wn * 32 + nt * 16 + l15) * KP + ks * 32 + quad * 8];
#pragma unroll
    for (int mt = 0; mt < 2; mt++)
#pragma unroll
      for (int nt = 0; nt < 2; nt++)
        acc[mt][nt] = __builtin_amdgcn_mfma_f32_16x16x32_f16(af[mt], bf[nt],
                                                             acc[mt][nt], 0, 0, 0);
  }
#pragma unroll
  for (int mt = 0; mt < 2; mt++)
#pragma unroll
    for (int nt = 0; nt < 2; nt++)
#pragma unroll
      for (int r = 0; r < 4; r++) {
        int lrow = wm * 32 + mt * 16 + quad * 4 + r;
        int row = m0 + lrow;
        int col = wn * 32 + nt * 16 + l15;
        int l = row & (LL - 1);
        float v = acc[mt][nt][r] +
            pos_tab[(l >> 6) * 64 + col] + type_tab[(l & 63) * 64 + col];
        x1[(size_t)row * 64 + col] = v;
        xs[SW64(lrow, col)] = (_Float16)v;
      }
  __syncthreads();
  qkv_phase(xs, wqkvf, bqkv, qbuf, kbuf, vbuf, bx, wave, lane);
}

// ------- attention: coalesced K/V staging; output in A-fragment-linear layout -------
__global__ __launch_bounds__(256) void k_attn2(
    const _Float16* __restrict__ qbuf, const _Float16* __restrict__ kbuf,
    const _Float16* __restrict__ vbuf, const float* __restrict__ zm,
    _Float16* __restrict__ obuf)
{
  __shared__ _Float16 Ks[1024 * 8];
  __shared__ _Float16 Vs[1024 * 8];
  __shared__ float zs[1024];
  int blk = blockIdx.x;
  int qb = blk & 3, h = (blk >> 2) & 7, b = blk >> 5;
  const _Float16* kb = kbuf + (size_t)(b * 8 + h) * 8192;
  const _Float16* vb = vbuf + (size_t)(b * 8 + h) * 8192;
  for (int p = threadIdx.x; p < 1024; p += 256) {
    *(half8*)&Ks[p * 8] = *(const half8*)&kb[p * 8];
    *(half8*)&Vs[p * 8] = *(const half8*)&vb[p * 8];
    zs[p] = zm[b * LL + p];
  }
  __syncthreads();
  int qrow = qb * 256 + threadIdx.x;
  int tq = qrow >> 6, vq = qrow & 63;
  half8 qh = *(const half8*)&qbuf[(size_t)(b * LL + qrow) * 64 + h * 8];
  const float scale = 0.3535533905932738f;
  float m = -INFINITY, lsum = 0.f;
  float acc[8] = {0.f, 0.f, 0.f, 0.f, 0.f, 0.f, 0.f, 0.f};
  bool zmq = (zs[qrow] != 0.f);

  auto attend = [&](int k) {
    if (zs[k] != 0.f) return;
    half8 kk = *(const half8*)&Ks[k * 8];
    float s = 0.f;
#ifdef HAVE_FDOT2
#pragma unroll
    for (int j = 0; j < 4; j++) {
      half2v qa = (half2v){qh[2 * j], qh[2 * j + 1]};
      half2v ka = (half2v){kk[2 * j], kk[2 * j + 1]};
      s = __builtin_amdgcn_fdot2(qa, ka, s, false);
    }
#else
#pragma unroll
    for (int j = 0; j < 8; j++) s += (float)qh[j] * (float)kk[j];
#endif
    s *= scale;
    half8 vv = *(const half8*)&Vs[k * 8];
    if (s <= m) {
      float p = __expf(s - m);
      lsum += p;
#pragma unroll
      for (int d = 0; d < 8; d++) acc[d] += p * (float)vv[d];
    } else {
      float r = __expf(m - s);
      lsum = lsum * r + 1.f;
#pragma unroll
      for (int d = 0; d < 8; d++) acc[d] = acc[d] * r + (float)vv[d];
      m = s;
    }
  };

  if (!zmq) {
    for (int vv = 0; vv < 64; vv++) attend(tq * 64 + vv);
    for (int tt = 0; tt < 16; tt++) {
      if (tt == tq) continue;
      attend(tt * 64 + vq);
    }
  }
  float inv = 1.f / lsum;
  half8 o;
#pragma unroll
  for (int d = 0; d < 8; d++) o[d] = (_Float16)(acc[d] * inv);
  size_t tile = (size_t)(b * 16 + (qrow >> 6));
  int frag = ((qrow >> 4) & 3) * 2 + (h >> 2);
  int flane = (h & 3) * 16 + (qrow & 15);
  *(half8*)&obuf[tile * 4096 + frag * 512 + flane * 8] = o;
}

// ---- fused o-proj + LN1 + FFN split: reads x1/obuf, split0 writes x2, partials->out ----
// grid (256, 4): blockIdx.x = row tile, blockIdx.y = hidden split (512 each).
__global__ __launch_bounds__(256) void k_olnffn(
    const _Float16* __restrict__ obuf, const _Float16* __restrict__ wof,
    const float* __restrict__ bo, const float* __restrict__ x1,
    float* __restrict__ x2, const float* __restrict__ ln_s,
    const float* __restrict__ ln_b, const _Float16* __restrict__ w1f,
    const _Float16* __restrict__ w2f, const float* __restrict__ b1,
    const float* __restrict__ b2, float* __restrict__ out)
{
  __shared__ char smem[17408];        // ots (64x68 f32) then hs dbuf (2x4096 f16)
  __shared__ _Float16 xs[4096];
  float* ots = (float*)smem;
  _Float16* hsb = (_Float16*)smem;
  int tid = threadIdx.x;
  int bx = blockIdx.x, split = blockIdx.y;
  int wave = tid >> 6, lane = tid & 63, quad = lane >> 4, l15 = lane & 15;
  int wm = wave >> 1, wn = wave & 1;

  // ---- oln ----
  const _Float16* ot = obuf + (size_t)bx * 4096;
  {
    half8 af[2][2], bf[2][2];
#pragma unroll
    for (int mt = 0; mt < 2; mt++)
#pragma unroll
      for (int ks = 0; ks < 2; ks++)
        af[mt][ks] = *(const half8*)&ot[(size_t)(((wm * 2 + mt) * 2 + ks) * 512) +
                                        lane * 8];
#pragma unroll
    for (int nt = 0; nt < 2; nt++)
#pragma unroll
      for (int ks = 0; ks < 2; ks++)
        bf[nt][ks] = *(const half8*)&wof[(size_t)(((wn * 2 + nt) * 2 + ks) * 512) +
                                         lane * 8];
    f32x4 acc[2][2];
#pragma unroll
    for (int mt = 0; mt < 2; mt++)
#pragma unroll
      for (int nt = 0; nt < 2; nt++) {
        float bv = bo[wn * 32 + nt * 16 + l15];
        acc[mt][nt] = (f32x4){bv, bv, bv, bv};
      }
#pragma unroll
    for (int ks = 0; ks < 2; ks++)
#pragma unroll
      for (int mt = 0; mt < 2; mt++)
#pragma unroll
        for (int nt = 0; nt < 2; nt++)
          acc[mt][nt] = __builtin_amdgcn_mfma_f32_16x16x32_f16(
              af[mt][ks], bf[nt][ks], acc[mt][nt], 0, 0, 0);
#pragma unroll
    for (int mt = 0; mt < 2; mt++)
#pragma unroll
      for (int nt = 0; nt < 2; nt++)
#pragma unroll
        for (int r = 0; r < 4; r++)
          ots[(wm * 32 + mt * 16 + quad * 4 + r) * 68 + wn * 32 + nt * 16 + l15] =
              acc[mt][nt][r];
  }
  __syncthreads();
  for (int i = 0; i < 16; i++) {
    int row = wave * 16 + i;
    size_t off = (size_t)(bx * 64 + row) * 64 + lane;
    float val = ots[row * 68 + lane] + x1[off];
    float sum = val;
#pragma unroll
    for (int o = 32; o > 0; o >>= 1) sum += __shfl_xor(sum, o);
    float mean = sum * (1.f / 64.f);
    float d = val - mean;
    float sq = d * d;
#pragma unroll
    for (int o = 32; o > 0; o >>= 1) sq += __shfl_xor(sq, o);
    float xv = d * rsqrtf(sq * (1.f / 64.f) + 1e-5f) * ln_s[lane] + ln_b[lane];
    if (split == 0) x2[off] = xv;
    xs[SW64(row, lane)] = (_Float16)xv;
  }
  __syncthreads();  // xs ready; all ots reads done -> hs may reuse smem

  // ---- ffn split ----
  const float* b1g = b1 + split * 512;
  half8 xb[2][2];
#pragma unroll
  for (int mt = 0; mt < 2; mt++)
#pragma unroll
    for (int ks = 0; ks < 2; ks++)
      xb[mt][ks] = *(const half8*)&xs[SW64(wn * 32 + mt * 16 + l15,
                                           ks * 32 + quad * 8)];
  f32x4 acc[2][2];
#pragma unroll
  for (int mt = 0; mt < 2; mt++)
#pragma unroll
    for (int nt = 0; nt < 2; nt++) {
      float bv = (split == 0) ? b2[wn * 32 + nt * 16 + l15] : 0.f;
      acc[mt][nt] = (f32x4){bv, bv, bv, bv};
    }
  int buf = 0;
  for (int c = 0; c < 8; c++) {
    int g = split * 8 + c;
    const _Float16* w1t_ = w1f + (size_t)g * 4096;
    const _Float16* w2t_ = w2f + (size_t)g * 4096;
    half8 a1[2][2], b2f[2][2];
#pragma unroll
    for (int ht = 0; ht < 2; ht++)
#pragma unroll
      for (int ks = 0; ks < 2; ks++)
        a1[ht][ks] = *(const half8*)&w1t_[(size_t)(((wm * 2 + ht) * 2 + ks) * 512) +
                                          lane * 8];
#pragma unroll
    for (int nt = 0; nt < 2; nt++)
#pragma unroll
      for (int ks = 0; ks < 2; ks++)
        b2f[nt][ks] = *(const half8*)&w2t_[(size_t)(((wn * 2 + nt) * 2 + ks) * 512) +
                                           lane * 8];
    f32x4 hacc[2][2];
#pragma unroll
    for (int ht = 0; ht < 2; ht++)
#pragma unroll
      for (int mt = 0; mt < 2; mt++) hacc[ht][mt] = (f32x4){0.f, 0.f, 0.f, 0.f};
#pragma unroll
    for (int ks = 0; ks < 2; ks++)
#pragma unroll
      for (int ht = 0; ht < 2; ht++)
#pragma unroll
        for (int mt = 0; mt < 2; mt++)
          hacc[ht][mt] = __builtin_amdgcn_mfma_f32_16x16x32_f16(
              a1[ht][ks], xb[mt][ks], hacc[ht][mt], 0, 0, 0);
#pragma unroll
    for (int ht = 0; ht < 2; ht++) {
      float4 bb = *(const float4*)&b1g[c * 64 + wm * 32 + ht * 16 + quad * 4];
#pragma unroll
      for (int mt = 0; mt < 2; mt++) {
        f32x4 hv = hacc[ht][mt];
        half4v hp = (half4v){
            (_Float16)fmaxf(hv[0] + bb.x, 0.f), (_Float16)fmaxf(hv[1] + bb.y, 0.f),
            (_Float16)fmaxf(hv[2] + bb.z, 0.f), (_Float16)fmaxf(hv[3] + bb.w, 0.f)};
        *(half4v*)&hsb[buf * 4096 + SW64(wn * 32 + mt * 16 + l15,
                                         wm * 32 + ht * 16 + quad * 4)] = hp;
      }
    }
    __syncthreads();
#pragma unroll
    for (int ks = 0; ks < 2; ks++)
#pragma unroll
      for (int mt = 0; mt < 2; mt++) {
        half8 a2 = *(const half8*)&hsb[buf * 4096 + SW64(wm * 32 + mt * 16 + l15,
                                                         ks * 32 + quad * 8)];
#pragma unroll
        for (int nt = 0; nt < 2; nt++)
          acc[mt][nt] = __builtin_amdgcn_mfma_f32_16x16x32_f16(a2, b2f[nt][ks],
                                                               acc[mt][nt], 0, 0, 0);
      }
    buf ^= 1;
  }
#pragma unroll
  for (int mt = 0; mt < 2; mt++)
#pragma unroll
    for (int nt = 0; nt < 2; nt++)
#pragma unroll
      for (int r = 0; r < 4; r++) {
        int row = bx * 64 + wm * 32 + mt * 16 + quad * 4 + r;
        int col = wn * 32 + nt * 16 + l15;
        out[(size_t)split * ((size_t)BL * 64) + (size_t)row * 64 + col] =
            acc[mt][nt][r];
      }
}

// ---- fused residual(4 parts)+LN2 -> x1, then QKV of next layer from LDS ----
__global__ __launch_bounds__(256) void k_reslnqkv(
    float* __restrict__ x1, const float* __restrict__ x2,
    const float* __restrict__ tmp, const float* __restrict__ sc,
    const float* __restrict__ bs, const _Float16* __restrict__ wqkvf,
    const float* __restrict__ bqkv, _Float16* __restrict__ qbuf,
    _Float16* __restrict__ kbuf, _Float16* __restrict__ vbuf, int doqkv)
{
  __shared__ _Float16 xs[4096];
  int tid = threadIdx.x;
  int bx = blockIdx.x;
  int wave = tid >> 6, lane = tid & 63;
  int sub = lane & 15, rg = lane >> 4;
#pragma unroll
  for (int i = 0; i < 4; i++) {
    int lrow = i * 16 + wave * 4 + rg;
    size_t off = (size_t)(bx * 64 + lrow) * 64 + sub * 4;
    float4 v = *(const float4*)&x2[off];
#pragma unroll
    for (int p = 0; p < 4; p++) {
      float4 t = *(const float4*)&tmp[(size_t)p * ((size_t)BL * 64) + off];
      v.x += t.x; v.y += t.y; v.z += t.z; v.w += t.w;
    }
    float sum = v.x + v.y + v.z + v.w;
#pragma unroll
    for (int o = 1; o < 16; o <<= 1) sum += __shfl_xor(sum, o);
    float mean = sum * (1.f / 64.f);
    float4 d = {v.x - mean, v.y - mean, v.z - mean, v.w - mean};
    float sq = d.x * d.x + d.y * d.y + d.z * d.z + d.w * d.w;
#pragma unroll
    for (int o = 1; o < 16; o <<= 1) sq += __shfl_xor(sq, o);
    float rs = rsqrtf(sq * (1.f / 64.f) + 1e-5f);
    float4 s4 = *(const float4*)&sc[sub * 4];
    float4 b4 = *(const float4*)&bs[sub * 4];
    float4 o4 = {d.x * rs * s4.x + b4.x, d.y * rs * s4.y + b4.y,
                 d.z * rs * s4.z + b4.z, d.w * rs * s4.w + b4.w};
    *(float4*)&x1[off] = o4;
    half4v hp = (half4v){(_Float16)o4.x, (_Float16)o4.y,
                         (_Float16)o4.z, (_Float16)o4.w};
    *(half4v*)&xs[SW64(lrow, sub * 4)] = hp;
  }
  if (!doqkv) return;
  __syncthreads();
  qkv_phase(xs, wqkvf, bqkv, qbuf, kbuf, vbuf, bx, wave, lane);
}

// ---------------- head: out[B,V,3] = x[:, -1] @ W_head + b_head ----------------
__global__ __launch_bounds__(256) void k_head(
    const float* __restrict__ x, const float* __restrict__ Wh,
    const float* __restrict__ bh, float* __restrict__ out)
{
  int id = blockIdx.x * 256 + threadIdx.x;  // < B*V = 1024
  int b = id >> 6, v = id & 63;
  const float* xr = x + (size_t)(b * LL + (SS - 1) * VVV + v) * 64;
  float a0 = bh[0], a1 = bh[1], a2 = bh[2];
  for (int e = 0; e < 64; e++) {
    float xv = xr[e];
    a0 += xv * Wh[e * 3 + 0];
    a1 += xv * Wh[e * 3 + 1];
    a2 += xv * Wh[e * 3 + 2];
  }
  out[id * 3 + 0] = a0;
  out[id * 3 + 1] = a1;
  out[id * 3 + 2] = a2;
}

extern "C" void kernel_launch(void* const* d_in, const int* in_sizes, int n_in,
                              void* d_out, int out_size, void* d_ws, size_t ws_size,
                              hipStream_t stream) {
  const float* features = (const float*)d_in[0];
  const int*   ovtag    = (const int*)d_in[1];
  const int*   poiid    = (const int*)d_in[2];
  const float* W_raw    = (const float*)d_in[3];
  const float* b_raw    = (const float*)d_in[4];
  const float* pos_tab  = (const float*)d_in[5];
  const float* type_tab = (const float*)d_in[6];
  const float* poi_tab  = (const float*)d_in[7];
  const float* ov_tab   = (const float*)d_in[8];
  const float* W_comb   = (const float*)d_in[9];
  const float* b_comb   = (const float*)d_in[10];
  const float* Wqkv     = (const float*)d_in[11];
  const float* bqkv     = (const float*)d_in[12];
  const float* Wo       = (const float*)d_in[13];
  const float* bo       = (const float*)d_in[14];
  const float* ln1_s    = (const float*)d_in[15];
  const float* ln1_b    = (const float*)d_in[16];
  const float* W1       = (const float*)d_in[17];
  const float* b1       = (const float*)d_in[18];
  const float* W2       = (const float*)d_in[19];
  const float* b2       = (const float*)d_in[20];
  const float* ln2_s    = (const float*)d_in[21];
  const float* ln2_b    = (const float*)d_in[22];
  const float* W_head   = (const float*)d_in[23];
  const float* b_head   = (const float*)d_in[24];
  float* out = (float*)d_out;
  float* ws  = (float*)d_ws;

  float* zm  = ws;                              // BL
  float* x1  = zm + BL;                         // BL*64 (pre-attn / post-LN2)
  float* x2  = x1 + (size_t)BL * 64;            // BL*64 (post-LN1)
  float* tmp = x2 + (size_t)BL * 64;            // 4 * BL*64
  _Float16* qbuf   = (_Float16*)(tmp + 4 * (size_t)BL * 64);  // BL*64
  _Float16* kbuf   = qbuf + (size_t)BL * 64;                  // BL*64
  _Float16* vbuf   = kbuf + (size_t)BL * 64;                  // BL*64
  _Float16* obuf16 = vbuf + (size_t)BL * 64;                  // BL*64 (frag-linear)
  _Float16* wcombt = obuf16 + (size_t)BL * 64;                // 64*80
  _Float16* w1f    = wcombt + 5120;                           // NL*PERL
  _Float16* w2f    = w1f + (size_t)NLAYER * PERL;             // NL*PERL
  _Float16* wqkvf  = w2f + (size_t)NLAYER * PERL;             // NL*3*4096
  _Float16* wof    = wqkvf + (size_t)NLAYER * 3 * 4096;       // NL*4096

  k_prep<<<274, 256, 0, stream>>>(W1, W2, Wqkv, Wo, W_comb,
                                  w1f, w2f, wqkvf, wof, wcombt);
  k_embqkv<<<256, 256, 0, stream>>>(features, ovtag, poiid, W_raw, b_raw,
                                    ov_tab, poi_tab, wcombt, b_comb,
                                    pos_tab, type_tab, x1, zm,
                                    wqkvf, bqkv, qbuf, kbuf, vbuf);
  for (int l = 0; l < NLAYER; l++) {
    k_attn2<<<512, 256, 0, stream>>>(qbuf, kbuf, vbuf, zm, obuf16);
    k_olnffn<<<dim3(256, 4), 256, 0, stream>>>(
        obuf16, wof + (size_t)l * 4096, bo + l * EE, x1, x2,
        ln1_s + l * EE, ln1_b + l * EE,
        w1f + (size_t)l * PERL, w2f + (size_t)l * PERL,
        b1 + l * DFF_, b2 + l * EE, tmp);
    int doqkv = (l < NLAYER - 1);
    k_reslnqkv<<<256, 256, 0, stream>>>(
        x1, x2, tmp, ln2_s + l * EE, ln2_b + l * EE,
        wqkvf + (size_t)(l + 1) * 3 * 4096, bqkv + (l + 1) * 192,
        qbuf, kbuf, vbuf, doqkv);
  }
  k_head<<<4, 256, 0, stream>>>(x1, W_head, b_head, out);
}

// Round 9
// 311.636 us; speedup vs baseline: 1.9730x; 1.1558x over previous
//
#include <hip/hip_runtime.h>
#include <math.h>

#define BB 16
#define SS 16
#define VVV 64
#define EE 64
#define HHH 8
#define NLAYER 4
#define DFF_ 2048
#define LL 1024   /* S*V */
#define BL 16384  /* B*L */
#define PERL 131072  /* 64*2048 elems per layer of W1 (and W2); 32 tiles*4096 */

typedef __attribute__((ext_vector_type(8))) _Float16 half8;
typedef __attribute__((ext_vector_type(4))) _Float16 half4v;
typedef __attribute__((ext_vector_type(2))) _Float16 half2v;
typedef __attribute__((ext_vector_type(4))) float f32x4;

#if defined(__has_builtin)
#if __has_builtin(__builtin_amdgcn_fdot2)
#define HAVE_FDOT2 1
#endif
#endif

// XOR-swizzled index into row-major fp16 LDS tiles with 64-half (128 B) rows.
#define SW64(m, k)  (((m) << 6) + ((((k) >> 3) ^ ((m) & 7)) << 3) + ((k) & 7))

// Fragment-linear tile layout (64x64 fp16 = 8 frags of 512 halves):
//   A[m][k] -> frag = (m>>4)*2 + (k>>5); lane = ((k>>3)&3)*16 + (m&15); +(k&7)
// Wave loading frag f reads tile_base + f*512 + lane*8 -> contiguous 1 KB.

// ---------------- prep: weights -> fp16 fragment-linear tiles (one dispatch) ----------
__global__ __launch_bounds__(256) void k_prep(
    const float* __restrict__ W1, const float* __restrict__ W2,
    const float* __restrict__ Wqkv, const float* __restrict__ Wo,
    const float* __restrict__ Wcomb,
    _Float16* __restrict__ w1f, _Float16* __restrict__ w2f,
    _Float16* __restrict__ wqkvf, _Float16* __restrict__ wof,
    _Float16* __restrict__ wcombt)
{
  __shared__ float t[64 * 65];
  int bx = blockIdx.x;
  int cc = threadIdx.x & 63, rr = threadIdx.x >> 6;

  if (bx >= 272) {  // Wcomb [80][64] -> wcombt [64][80]
    int r0 = (bx - 272) * 64;
#pragma unroll
    for (int i = 0; i < 16; i++) {
      int r = i * 4 + rr;
      if (r0 + r < 80) t[r * 65 + cc] = Wcomb[(size_t)(r0 + r) * 64 + cc];
    }
    __syncthreads();
#pragma unroll
    for (int i = 0; i < 16; i++) {
      int c = i * 4 + rr;
      if (r0 + c < 80) wcombt[(size_t)cc * 80 + r0 + c] = (_Float16)t[c * 65 + cc];
    }
    return;
  }

  const float* src; _Float16* dst; int astr;
  if (bx < 128) {        // W1 [64 k][2048 hid]: tile g = hid block
    int l = bx >> 5, g = bx & 31;
    src = W1 + (size_t)l * PERL + g * 64; astr = 2048;
    dst = w1f + (size_t)(l * 32 + g) * 4096;
  } else if (bx < 256) { // W2 [2048 k][64 n]: tile g = k block
    int j = bx - 128; int l = j >> 5, g = j & 31;
    src = W2 + (size_t)l * PERL + (size_t)g * 64 * 64; astr = 64;
    dst = w2f + (size_t)(l * 32 + g) * 4096;
  } else if (bx < 268) { // Wqkv [64 k][192 n]: 3 tiles per layer
    int j = bx - 256; int l = j / 3, g = j % 3;
    src = Wqkv + (size_t)l * 64 * 192 + g * 64; astr = 192;
    dst = wqkvf + (size_t)(l * 3 + g) * 4096;
  } else {               // Wo [64 k][64 n]
    int l = bx - 268;
    src = Wo + (size_t)l * 4096; astr = 64;
    dst = wof + (size_t)l * 4096;
  }
#pragma unroll
  for (int i = 0; i < 16; i++) {
    int a = i * 4 + rr;
    t[cc * 65 + a] = src[(size_t)a * astr + cc];  // t[m][k] = S[k][m]
  }
  __syncthreads();
#pragma unroll
  for (int it = 0; it < 2; it++) {
    int c = threadIdx.x + it * 256;
    int frag = c >> 6, lane = c & 63;
    int m = (frag >> 1) * 16 + (lane & 15);
    int k0 = (frag & 1) * 32 + (lane >> 4) * 8;
    const float* tr = &t[m * 65 + k0];
    half8 h;
#pragma unroll
    for (int j = 0; j < 8; j++) h[j] = (_Float16)tr[j];
    *(half8*)&dst[(size_t)c * 8] = h;
  }
}

// ---- shared QKV GEMM body for one n-block (used by embqkv 4-wave and k_layer) ----
__device__ __forceinline__ void qkv_nb(
    const half8 af[2][2], const _Float16* __restrict__ wqkvf,
    const float* __restrict__ bqkv, _Float16* __restrict__ qbuf,
    _Float16* __restrict__ kbuf, _Float16* __restrict__ vbuf,
    int bx, int nb, int wm, int wn, int lane)
{
  int quad = lane >> 4, l15 = lane & 15;
  const _Float16* bt = wqkvf + (size_t)nb * 4096;
  half8 bf[2][2];
#pragma unroll
  for (int nt = 0; nt < 2; nt++)
#pragma unroll
    for (int ks = 0; ks < 2; ks++)
      bf[nt][ks] = *(const half8*)&bt[(size_t)(((wn * 2 + nt) * 2 + ks) * 512) +
                                      lane * 8];
  f32x4 acc[2][2];
#pragma unroll
  for (int mt = 0; mt < 2; mt++)
#pragma unroll
    for (int nt = 0; nt < 2; nt++) {
      float bv = bqkv[nb * 64 + wn * 32 + nt * 16 + l15];
      acc[mt][nt] = (f32x4){bv, bv, bv, bv};
    }
#pragma unroll
  for (int ks = 0; ks < 2; ks++)
#pragma unroll
    for (int mt = 0; mt < 2; mt++)
#pragma unroll
      for (int nt = 0; nt < 2; nt++)
        acc[mt][nt] = __builtin_amdgcn_mfma_f32_16x16x32_f16(
            af[mt][ks], bf[nt][ks], acc[mt][nt], 0, 0, 0);
#pragma unroll
  for (int mt = 0; mt < 2; mt++)
#pragma unroll
    for (int nt = 0; nt < 2; nt++) {
      int col = wn * 32 + nt * 16 + l15;
#pragma unroll
      for (int r = 0; r < 4; r++) {
        int row = bx * 64 + wm * 32 + mt * 16 + quad * 4 + r;
        _Float16 v = (_Float16)acc[mt][nt][r];
        if (nb == 0) {
          qbuf[(size_t)row * 64 + col] = v;
        } else {
          _Float16* dst = (nb == 1) ? kbuf : vbuf;
          int h = col >> 3, d = col & 7;
          int b = row >> 10, rb = row & 1023;
          dst[((size_t)(b * 8 + h) * 1024 + rb) * 8 + d] = v;
        }
      }
    }
}

// ------- fused embed + comb GEMM + pos/type + QKV(layer0): writes x1, zm, q/k/v -------
__global__ __launch_bounds__(256) void k_embqkv(
    const float* __restrict__ features, const int* __restrict__ ovtag,
    const int* __restrict__ poiid, const float* __restrict__ W_raw,
    const float* __restrict__ b_raw, const float* __restrict__ ov_tab,
    const float* __restrict__ poi_tab, const _Float16* __restrict__ wcombt,
    const float* __restrict__ b_comb, const float* __restrict__ pos_tab,
    const float* __restrict__ type_tab, float* __restrict__ x1,
    float* __restrict__ zm, const _Float16* __restrict__ wqkvf,
    const float* __restrict__ bqkv, _Float16* __restrict__ qbuf,
    _Float16* __restrict__ kbuf, _Float16* __restrict__ vbuf)
{
  constexpr int KP = 104;
  __shared__ _Float16 As[64 * KP];
  __shared__ _Float16 Bs[64 * KP];
  __shared__ _Float16 xs[4096];
  int tid = threadIdx.x;
  int bx = blockIdx.x;
  int m0 = bx * 64;
  int wave = tid >> 6, lane = tid & 63, quad = lane >> 4, l15 = lane & 15;
  int wm = wave >> 1, wn = wave & 1;
  for (int p = tid; p < 1536; p += 256) {
    int r = p / 24, s = p - r * 24; int c = s * 4;
    int row = m0 + r;
    float f0 = features[row * 3 + 0];
    float f1 = features[row * 3 + 1];
    float f2 = features[row * 3 + 2];
    if (s == 0) zm[row] = ((f0 + f1 + f2) == 0.f) ? 1.f : 0.f;
    half4v h;
#pragma unroll
    for (int j = 0; j < 4; j++) {
      int cc = c + j; float v;
      if (cc < 64) {
        v = b_raw[cc] + f0 * W_raw[cc] + f1 * W_raw[64 + cc] + f2 * W_raw[128 + cc];
      } else if (cc < 72) {
        int tt = ovtag[row]; v = (tt <= 0) ? 0.f : ov_tab[tt * 8 + cc - 64];
      } else if (cc < 80) {
        int tt = poiid[row]; v = (tt <= 0) ? 0.f : poi_tab[tt * 8 + cc - 72];
      } else v = 0.f;
      h[j] = (_Float16)v;
    }
    *(half4v*)&As[r * KP + c] = h;
  }
  for (int p = tid; p < 1536; p += 256) {
    int r = p / 24, s = p - r * 24; int c = s * 4;
    half4v h = (half4v){0, 0, 0, 0};
    if (c < 80) h = *(const half4v*)&wcombt[r * 80 + c];
    *(half4v*)&Bs[r * KP + c] = h;
  }
  __syncthreads();
  f32x4 acc[2][2];
#pragma unroll
  for (int mt = 0; mt < 2; mt++)
#pragma unroll
    for (int nt = 0; nt < 2; nt++) {
      float bv = b_comb[wn * 32 + nt * 16 + l15];
      acc[mt][nt] = (f32x4){bv, bv, bv, bv};
    }
#pragma unroll
  for (int ks = 0; ks < 3; ks++) {
    half8 af[2], bf[2];
#pragma unroll
    for (int mt = 0; mt < 2; mt++)
      af[mt] = *(const half8*)&As[(wm * 32 + mt * 16 + l15) * KP + ks * 32 + quad * 8];
#pragma unroll
    for (int nt = 0; nt < 2; nt++)
      bf[nt] = *(const half8*)&Bs[(wn * 32 + nt * 16 + l15) * KP + ks * 32 + quad * 8];
#pragma unroll
    for (int mt = 0; mt < 2; mt++)
#pragma unroll
      for (int nt = 0; nt < 2; nt++)
        acc[mt][nt] = __builtin_amdgcn_mfma_f32_16x16x32_f16(af[mt], bf[nt],
                                                             acc[mt][nt], 0, 0, 0);
  }
#pragma unroll
  for (int mt = 0; mt < 2; mt++)
#pragma unroll
    for (int nt = 0; nt < 2; nt++)
#pragma unroll
      for (int r = 0; r < 4; r++) {
        int lrow = wm * 32 + mt * 16 + quad * 4 + r;
        int row = m0 + lrow;
        int col = wn * 32 + nt * 16 + l15;
        int l = row & (LL - 1);
        float v = acc[mt][nt][r] +
            pos_tab[(l >> 6) * 64 + col] + type_tab[(l & 63) * 64 + col];
        x1[(size_t)row * 64 + col] = v;
        xs[SW64(lrow, col)] = (_Float16)v;
      }
  __syncthreads();
  half8 af[2][2];
#pragma unroll
  for (int mt = 0; mt < 2; mt++)
#pragma unroll
    for (int ks = 0; ks < 2; ks++)
      af[mt][ks] = *(const half8*)&xs[SW64(wm * 32 + mt * 16 + l15,
                                           ks * 32 + quad * 8)];
  for (int nb = 0; nb < 3; nb++)
    qkv_nb(af, wqkvf, bqkv, qbuf, kbuf, vbuf, bx, nb, wm, wn, lane);
}

// ------- attention: coalesced K/V staging; output in A-fragment-linear layout -------
__global__ __launch_bounds__(256) void k_attn2(
    const _Float16* __restrict__ qbuf, const _Float16* __restrict__ kbuf,
    const _Float16* __restrict__ vbuf, const float* __restrict__ zm,
    _Float16* __restrict__ obuf)
{
  __shared__ _Float16 Ks[1024 * 8];
  __shared__ _Float16 Vs[1024 * 8];
  __shared__ float zs[1024];
  int blk = blockIdx.x;
  int qb = blk & 3, h = (blk >> 2) & 7, b = blk >> 5;
  const _Float16* kb = kbuf + (size_t)(b * 8 + h) * 8192;
  const _Float16* vb = vbuf + (size_t)(b * 8 + h) * 8192;
  for (int p = threadIdx.x; p < 1024; p += 256) {
    *(half8*)&Ks[p * 8] = *(const half8*)&kb[p * 8];
    *(half8*)&Vs[p * 8] = *(const half8*)&vb[p * 8];
    zs[p] = zm[b * LL + p];
  }
  __syncthreads();
  int qrow = qb * 256 + threadIdx.x;
  int tq = qrow >> 6, vq = qrow & 63;
  half8 qh = *(const half8*)&qbuf[(size_t)(b * LL + qrow) * 64 + h * 8];
  const float scale = 0.3535533905932738f;
  float m = -INFINITY, lsum = 0.f;
  float acc[8] = {0.f, 0.f, 0.f, 0.f, 0.f, 0.f, 0.f, 0.f};
  bool zmq = (zs[qrow] != 0.f);

  auto attend = [&](int k) {
    if (zs[k] != 0.f) return;
    half8 kk = *(const half8*)&Ks[k * 8];
    float s = 0.f;
#ifdef HAVE_FDOT2
#pragma unroll
    for (int j = 0; j < 4; j++) {
      half2v qa = (half2v){qh[2 * j], qh[2 * j + 1]};
      half2v ka = (half2v){kk[2 * j], kk[2 * j + 1]};
      s = __builtin_amdgcn_fdot2(qa, ka, s, false);
    }
#else
#pragma unroll
    for (int j = 0; j < 8; j++) s += (float)qh[j] * (float)kk[j];
#endif
    s *= scale;
    half8 vv = *(const half8*)&Vs[k * 8];
    if (s <= m) {
      float p = __expf(s - m);
      lsum += p;
#pragma unroll
      for (int d = 0; d < 8; d++) acc[d] += p * (float)vv[d];
    } else {
      float r = __expf(m - s);
      lsum = lsum * r + 1.f;
#pragma unroll
      for (int d = 0; d < 8; d++) acc[d] = acc[d] * r + (float)vv[d];
      m = s;
    }
  };

  if (!zmq) {
    for (int vv = 0; vv < 64; vv++) attend(tq * 64 + vv);
    for (int tt = 0; tt < 16; tt++) {
      if (tt == tq) continue;
      attend(tt * 64 + vq);
    }
  }
  float inv = 1.f / lsum;
  half8 o;
#pragma unroll
  for (int d = 0; d < 8; d++) o[d] = (_Float16)(acc[d] * inv);
  size_t tile = (size_t)(b * 16 + (qrow >> 6));
  int frag = ((qrow >> 4) & 3) * 2 + (h >> 2);
  int flane = (h & 3) * 16 + (qrow & 15);
  *(half8*)&obuf[tile * 4096 + frag * 512 + flane * 8] = o;
}

// ---- layer megakernel (512 thr): oln + LN1 + full FFN + residual + LN2 + next QKV ----
// grid 256; waves split into 2 groups of 4; groups interleave even/odd hidden chunks.
__global__ __launch_bounds__(512) void k_layer(
    const _Float16* __restrict__ obuf, const _Float16* __restrict__ wof,
    const float* __restrict__ bo, float* __restrict__ x1,
    const float* __restrict__ ln1_s, const float* __restrict__ ln1_b,
    const _Float16* __restrict__ w1f, const _Float16* __restrict__ w2f,
    const float* __restrict__ b1, const float* __restrict__ b2,
    const float* __restrict__ ln2_s, const float* __restrict__ ln2_b,
    const _Float16* __restrict__ wqkvf, const float* __restrict__ bqkv,
    _Float16* __restrict__ qbuf, _Float16* __restrict__ kbuf,
    _Float16* __restrict__ vbuf, int doqkv)
{
  __shared__ float ots[64 * 68];          // 17.4 KB
  __shared__ _Float16 xs[4096];           // 8 KB  (post-LN1 fp16, FFN/QKV input)
  __shared__ float x2f[4096];             // 16 KB (post-LN1 fp32, LN2 residual)
  __shared__ _Float16 hs[2][2][4096];     // 32 KB ([grp][dbuf])
  int tid = threadIdx.x;
  int bx = blockIdx.x;
  int wave = tid >> 6, lane = tid & 63;
  int quad = lane >> 4, l15 = lane & 15;
  int grp = wave >> 2, w4 = wave & 3;
  int wm = w4 >> 1, wn = w4 & 1;

  // ---- o-proj (8 waves: m-quarter = grp*2+wm, n-half = wn) ----
  {
    const _Float16* ot = obuf + (size_t)bx * 4096;
    int mq = grp * 2 + wm;
    half8 af[2], bf[2][2];
#pragma unroll
    for (int ks = 0; ks < 2; ks++)
      af[ks] = *(const half8*)&ot[(size_t)((mq * 2 + ks) * 512) + lane * 8];
#pragma unroll
    for (int nt = 0; nt < 2; nt++)
#pragma unroll
      for (int ks = 0; ks < 2; ks++)
        bf[nt][ks] = *(const half8*)&wof[(size_t)(((wn * 2 + nt) * 2 + ks) * 512) +
                                         lane * 8];
    f32x4 acc[2];
#pragma unroll
    for (int nt = 0; nt < 2; nt++) {
      float bv = bo[wn * 32 + nt * 16 + l15];
      acc[nt] = (f32x4){bv, bv, bv, bv};
    }
#pragma unroll
    for (int ks = 0; ks < 2; ks++)
#pragma unroll
      for (int nt = 0; nt < 2; nt++)
        acc[nt] = __builtin_amdgcn_mfma_f32_16x16x32_f16(af[ks], bf[nt][ks],
                                                         acc[nt], 0, 0, 0);
#pragma unroll
    for (int nt = 0; nt < 2; nt++)
#pragma unroll
      for (int r = 0; r < 4; r++)
        ots[(mq * 16 + quad * 4 + r) * 68 + wn * 32 + nt * 16 + l15] = acc[nt][r];
  }
  __syncthreads();
  // ---- residual + LN1 (8 waves x 8 rows) ----
  for (int i = 0; i < 8; i++) {
    int row = wave * 8 + i;
    size_t off = (size_t)(bx * 64 + row) * 64 + lane;
    float val = ots[row * 68 + lane] + x1[off];
    float sum = val;
#pragma unroll
    for (int o = 32; o > 0; o >>= 1) sum += __shfl_xor(sum, o);
    float mean = sum * (1.f / 64.f);
    float d = val - mean;
    float sq = d * d;
#pragma unroll
    for (int o = 32; o > 0; o >>= 1) sq += __shfl_xor(sq, o);
    float xv = d * rsqrtf(sq * (1.f / 64.f) + 1e-5f) * ln1_s[lane] + ln1_b[lane];
    x2f[row * 64 + lane] = xv;
    xs[SW64(row, lane)] = (_Float16)xv;
  }
  __syncthreads();

  // ---- FFN, full hidden; group g handles chunks 2i+g, i = 0..15 ----
  half8 xb[2][2];
#pragma unroll
  for (int mt = 0; mt < 2; mt++)
#pragma unroll
    for (int ks = 0; ks < 2; ks++)
      xb[mt][ks] = *(const half8*)&xs[SW64(wn * 32 + mt * 16 + l15,
                                           ks * 32 + quad * 8)];
  f32x4 acc[2][2];
#pragma unroll
  for (int mt = 0; mt < 2; mt++)
#pragma unroll
    for (int nt = 0; nt < 2; nt++) {
      float bv = (grp == 0) ? b2[wn * 32 + nt * 16 + l15] : 0.f;
      acc[mt][nt] = (f32x4){bv, bv, bv, bv};
    }
  half8 a1[2][2][2], b2w[2][2][2];   // [stage][..][ks]
  auto loadw = [&](int st, int g) {
    const _Float16* w1t_ = w1f + (size_t)g * 4096;
    const _Float16* w2t_ = w2f + (size_t)g * 4096;
#pragma unroll
    for (int ht = 0; ht < 2; ht++)
#pragma unroll
      for (int ks = 0; ks < 2; ks++)
        a1[st][ht][ks] = *(const half8*)&w1t_[(size_t)(((wm * 2 + ht) * 2 + ks) * 512) +
                                              lane * 8];
#pragma unroll
    for (int nt = 0; nt < 2; nt++)
#pragma unroll
      for (int ks = 0; ks < 2; ks++)
        b2w[st][nt][ks] = *(const half8*)&w2t_[(size_t)(((wn * 2 + nt) * 2 + ks) * 512) +
                                               lane * 8];
  };
  loadw(0, grp);
  for (int i = 0; i < 16; i++) {
    int cur = i & 1;
    if (i < 15) loadw(cur ^ 1, (i + 1) * 2 + grp);   // prefetch next chunk
    int g = i * 2 + grp;
    f32x4 hacc[2][2];
#pragma unroll
    for (int ht = 0; ht < 2; ht++)
#pragma unroll
      for (int mt = 0; mt < 2; mt++) hacc[ht][mt] = (f32x4){0.f, 0.f, 0.f, 0.f};
#pragma unroll
    for (int ks = 0; ks < 2; ks++)
#pragma unroll
      for (int ht = 0; ht < 2; ht++)
#pragma unroll
        for (int mt = 0; mt < 2; mt++)
          hacc[ht][mt] = __builtin_amdgcn_mfma_f32_16x16x32_f16(
              a1[cur][ht][ks], xb[mt][ks], hacc[ht][mt], 0, 0, 0);
#pragma unroll
    for (int ht = 0; ht < 2; ht++) {
      float4 bb = *(const float4*)&b1[g * 64 + wm * 32 + ht * 16 + quad * 4];
#pragma unroll
      for (int mt = 0; mt < 2; mt++) {
        f32x4 hv = hacc[ht][mt];
        half4v hp = (half4v){
            (_Float16)fmaxf(hv[0] + bb.x, 0.f), (_Float16)fmaxf(hv[1] + bb.y, 0.f),
            (_Float16)fmaxf(hv[2] + bb.z, 0.f), (_Float16)fmaxf(hv[3] + bb.w, 0.f)};
        *(half4v*)&hs[grp][cur][SW64(wn * 32 + mt * 16 + l15,
                                     wm * 32 + ht * 16 + quad * 4)] = hp;
      }
    }
    __syncthreads();
#pragma unroll
    for (int ks = 0; ks < 2; ks++)
#pragma unroll
      for (int mt = 0; mt < 2; mt++) {
        half8 a2 = *(const half8*)&hs[grp][cur][SW64(wm * 32 + mt * 16 + l15,
                                                     ks * 32 + quad * 8)];
#pragma unroll
        for (int nt = 0; nt < 2; nt++)
          acc[mt][nt] = __builtin_amdgcn_mfma_f32_16x16x32_f16(a2, b2w[cur][nt][ks],
                                                               acc[mt][nt], 0, 0, 0);
      }
  }
  // ---- cross-group reduce into ots ----
  __syncthreads();
  if (grp == 0) {
#pragma unroll
    for (int mt = 0; mt < 2; mt++)
#pragma unroll
      for (int nt = 0; nt < 2; nt++)
#pragma unroll
        for (int r = 0; r < 4; r++)
          ots[(wm * 32 + mt * 16 + quad * 4 + r) * 68 + wn * 32 + nt * 16 + l15] =
              acc[mt][nt][r];
  }
  __syncthreads();
  if (grp == 1) {
#pragma unroll
    for (int mt = 0; mt < 2; mt++)
#pragma unroll
      for (int nt = 0; nt < 2; nt++)
#pragma unroll
        for (int r = 0; r < 4; r++)
          ots[(wm * 32 + mt * 16 + quad * 4 + r) * 68 + wn * 32 + nt * 16 + l15] +=
              acc[mt][nt][r];
  }
  __syncthreads();
  // ---- residual + LN2 -> x1 + xs ----
  for (int i = 0; i < 8; i++) {
    int row = wave * 8 + i;
    size_t off = (size_t)(bx * 64 + row) * 64 + lane;
    float val = ots[row * 68 + lane] + x2f[row * 64 + lane];
    float sum = val;
#pragma unroll
    for (int o = 32; o > 0; o >>= 1) sum += __shfl_xor(sum, o);
    float mean = sum * (1.f / 64.f);
    float d = val - mean;
    float sq = d * d;
#pragma unroll
    for (int o = 32; o > 0; o >>= 1) sq += __shfl_xor(sq, o);
    float xv = d * rsqrtf(sq * (1.f / 64.f) + 1e-5f) * ln2_s[lane] + ln2_b[lane];
    x1[off] = xv;
    xs[SW64(row, lane)] = (_Float16)xv;
  }
  if (!doqkv) return;
  __syncthreads();
  // ---- next layer's QKV (grp0: nb 0,2; grp1: nb 1) ----
  half8 af[2][2];
#pragma unroll
  for (int mt = 0; mt < 2; mt++)
#pragma unroll
    for (int ks = 0; ks < 2; ks++)
      af[mt][ks] = *(const half8*)&xs[SW64(wm * 32 + mt * 16 + l15,
                                           ks * 32 + quad * 8)];
  for (int nb = grp; nb < 3; nb += 2)
    qkv_nb(af, wqkvf, bqkv, qbuf, kbuf, vbuf, bx, nb, wm, wn, lane);
}

// ---------------- head: out[B,V,3] = x[:, -1] @ W_head + b_head ----------------
__global__ __launch_bounds__(256) void k_head(
    const float* __restrict__ x, const float* __restrict__ Wh,
    const float* __restrict__ bh, float* __restrict__ out)
{
  int id = blockIdx.x * 256 + threadIdx.x;  // < B*V = 1024
  int b = id >> 6, v = id & 63;
  const float* xr = x + (size_t)(b * LL + (SS - 1) * VVV + v) * 64;
  float a0 = bh[0], a1 = bh[1], a2 = bh[2];
  for (int e = 0; e < 64; e++) {
    float xv = xr[e];
    a0 += xv * Wh[e * 3 + 0];
    a1 += xv * Wh[e * 3 + 1];
    a2 += xv * Wh[e * 3 + 2];
  }
  out[id * 3 + 0] = a0;
  out[id * 3 + 1] = a1;
  out[id * 3 + 2] = a2;
}

extern "C" void kernel_launch(void* const* d_in, const int* in_sizes, int n_in,
                              void* d_out, int out_size, void* d_ws, size_t ws_size,
                              hipStream_t stream) {
  const float* features = (const float*)d_in[0];
  const int*   ovtag    = (const int*)d_in[1];
  const int*   poiid    = (const int*)d_in[2];
  const float* W_raw    = (const float*)d_in[3];
  const float* b_raw    = (const float*)d_in[4];
  const float* pos_tab  = (const float*)d_in[5];
  const float* type_tab = (const float*)d_in[6];
  const float* poi_tab  = (const float*)d_in[7];
  const float* ov_tab   = (const float*)d_in[8];
  const float* W_comb   = (const float*)d_in[9];
  const float* b_comb   = (const float*)d_in[10];
  const float* Wqkv     = (const float*)d_in[11];
  const float* bqkv     = (const float*)d_in[12];
  const float* Wo       = (const float*)d_in[13];
  const float* bo       = (const float*)d_in[14];
  const float* ln1_s    = (const float*)d_in[15];
  const float* ln1_b    = (const float*)d_in[16];
  const float* W1       = (const float*)d_in[17];
  const float* b1       = (const float*)d_in[18];
  const float* W2       = (const float*)d_in[19];
  const float* b2       = (const float*)d_in[20];
  const float* ln2_s    = (const float*)d_in[21];
  const float* ln2_b    = (const float*)d_in[22];
  const float* W_head   = (const float*)d_in[23];
  const float* b_head   = (const float*)d_in[24];
  float* out = (float*)d_out;
  float* ws  = (float*)d_ws;

  float* zm  = ws;                              // BL
  float* x1  = zm + BL;                         // BL*64
  _Float16* qbuf   = (_Float16*)(x1 + (size_t)BL * 64);       // BL*64
  _Float16* kbuf   = qbuf + (size_t)BL * 64;                  // BL*64
  _Float16* vbuf   = kbuf + (size_t)BL * 64;                  // BL*64
  _Float16* obuf16 = vbuf + (size_t)BL * 64;                  // BL*64 (frag-linear)
  _Float16* wcombt = obuf16 + (size_t)BL * 64;                // 64*80
  _Float16* w1f    = wcombt + 5120;                           // NL*PERL
  _Float16* w2f    = w1f + (size_t)NLAYER * PERL;             // NL*PERL
  _Float16* wqkvf  = w2f + (size_t)NLAYER * PERL;             // NL*3*4096
  _Float16* wof    = wqkvf + (size_t)NLAYER * 3 * 4096;       // NL*4096

  k_prep<<<274, 256, 0, stream>>>(W1, W2, Wqkv, Wo, W_comb,
                                  w1f, w2f, wqkvf, wof, wcombt);
  k_embqkv<<<256, 256, 0, stream>>>(features, ovtag, poiid, W_raw, b_raw,
                                    ov_tab, poi_tab, wcombt, b_comb,
                                    pos_tab, type_tab, x1, zm,
                                    wqkvf, bqkv, qbuf, kbuf, vbuf);
  for (int l = 0; l < NLAYER; l++) {
    k_attn2<<<512, 256, 0, stream>>>(qbuf, kbuf, vbuf, zm, obuf16);
    int doqkv = (l < NLAYER - 1);
    k_layer<<<256, 512, 0, stream>>>(
        obuf16, wof + (size_t)l * 4096, bo + l * EE, x1,
        ln1_s + l * EE, ln1_b + l * EE,
        w1f + (size_t)l * PERL, w2f + (size_t)l * PERL,
        b1 + l * DFF_, b2 + l * EE,
        ln2_s + l * EE, ln2_b + l * EE,
        wqkvf + (size_t)(l + 1) * 3 * 4096, bqkv + (l + 1) * 192,
        qbuf, kbuf, vbuf, doqkv);
  }
  k_head<<<4, 256, 0, stream>>>(x1, W_head, b_head, out);
}